// Round 1
// baseline (9948.765 us; speedup 1.0000x reference)
//
#include <hip/hip_runtime.h>
#include <cstdint>
#include <cstddef>

using u16 = unsigned short;
using u32 = unsigned int;

typedef __bf16 bf16x8 __attribute__((ext_vector_type(8)));
typedef float f32x4 __attribute__((ext_vector_type(4)));

#define DEV __device__ __forceinline__

constexpr float SS = 0.1f / 20.0f;  // STEP_SIZE = DT / N_STEPS

DEV float sigm(float x) { return 1.0f / (1.0f + __expf(-x)); }

DEV u16 f2bf(float f) {  // round-to-nearest-even f32 -> bf16
  union { float f; u32 u; } v; v.f = f;
  u32 r = v.u + 0x7FFFu + ((v.u >> 16) & 1u);
  return (u16)(r >> 16);
}
DEV float bf2f(u16 h) {
  union { u32 u; float f; } v; v.u = ((u32)h) << 16;
  return v.f;
}

// ---------------------------------------------------------------------------
// prep: optional copy / sigmoid(f32) / sigmoid(bf16) / raw bf16 convert
// ---------------------------------------------------------------------------
__global__ void k_prep(const float* __restrict__ in, float* __restrict__ fcopy,
                       float* __restrict__ sigf32, u16* __restrict__ sigb,
                       u16* __restrict__ rawb, int n) {
  int stride = gridDim.x * blockDim.x;
  for (int i = blockIdx.x * blockDim.x + threadIdx.x; i < n; i += stride) {
    float v = in[i];
    if (fcopy) fcopy[i] = v;
    if (rawb) rawb[i] = f2bf(v);
    if (sigf32 || sigb) {
      float s = sigm(v);
      if (sigf32) sigf32[i] = s;
      if (sigb) sigb[i] = f2bf(s);
    }
  }
}

// out[n][k] = bf16(in[k][n]);  in: K x N f32, K,N multiples of 32
__global__ void k_transpose_bf16(const float* __restrict__ in, u16* __restrict__ out,
                                 int K, int N) {
  __shared__ float tile[32][33];
  int kb = blockIdx.x * 32, nb = blockIdx.y * 32;
  int tx = threadIdx.x & 31, ty = threadIdx.x >> 5;  // 256 threads: 32x8
#pragma unroll
  for (int i = 0; i < 4; ++i)
    tile[ty + 8 * i][tx] = in[(size_t)(kb + ty + 8 * i) * N + nb + tx];
  __syncthreads();
#pragma unroll
  for (int i = 0; i < 4; ++i)
    out[(size_t)(nb + ty + 8 * i) * K + kb + tx] = f2bf(tile[tx][ty + 8 * i]);
}

// ---------------------------------------------------------------------------
// GEMM: C = A(MxK, bf16 row-major) * B(KxN) with B given as Bt = B^T (NxK,
// bf16 row-major). 128x128 tile, BK=64, 4 waves each 64x64, 16x16x32 MFMA.
// LDS XOR-swizzled (16B-slot index ^ row&7), applied on BOTH the
// global_load_lds source address and the ds_read address (rule #21).
// MODE 0: store acc to statef (f32, M x N)
// MODE 1: pre = acc + addc[m][n] + bias[n];   state update -> statef, sigb
// MODE 2: pre = acc + bias[n] + sum_k sig3[m][k]*w2[n*10+k]; update s2
// ---------------------------------------------------------------------------
template <int MODE>
__global__ void k_gemm(const u16* __restrict__ A, const u16* __restrict__ Bt,
                       int M, int N, int K,
                       const float* __restrict__ addc, const float* __restrict__ bias,
                       const float* __restrict__ sig3, const float* __restrict__ w2,
                       float* __restrict__ statef, u16* __restrict__ sigb) {
  constexpr int BM = 128, BN = 128, BK = 64;
  __shared__ __align__(16) u16 Als[BM * BK];
  __shared__ __align__(16) u16 Bls[BN * BK];
  int nbn = N / BN;
  int tm = (blockIdx.x / nbn) * BM;
  int tn = (blockIdx.x % nbn) * BN;
  int tid = threadIdx.x;
  int lane = tid & 63, wid = tid >> 6;
  int l15 = lane & 15, lhi = lane >> 4;
  int wm = (wid >> 1) * 64, wn = (wid & 1) * 64;

  f32x4 acc[4][4] = {};

  const u16* Ag = A + (size_t)tm * K;
  const u16* Bg = Bt + (size_t)tn * K;

  for (int k0 = 0; k0 < K; k0 += BK) {
    // stage 32KB: 4 rounds x 256 threads x 16B per matrix
#pragma unroll
    for (int rd = 0; rd < 4; ++rd) {
      int S = rd * 256 + tid;       // 16B slot index, linear in LDS
      int row = S >> 3;             // 8 slots (128B) per row of 64 bf16
      int cs = ((S & 7) ^ (row & 7)) * 8;  // pre-swizzled global column
      __builtin_amdgcn_global_load_lds(
          (const __attribute__((address_space(1))) u32*)(Ag + (size_t)row * K + k0 + cs),
          (__attribute__((address_space(3))) u32*)(Als + S * 8), 16, 0, 0);
      __builtin_amdgcn_global_load_lds(
          (const __attribute__((address_space(1))) u32*)(Bg + (size_t)row * K + k0 + cs),
          (__attribute__((address_space(3))) u32*)(Bls + S * 8), 16, 0, 0);
    }
    __syncthreads();
#pragma unroll
    for (int s = 0; s < 2; ++s) {
      bf16x8 af[4], bfr[4];
#pragma unroll
      for (int i = 0; i < 4; ++i) {
        int row = wm + i * 16 + l15;
        af[i] = *(const bf16x8*)(Als + row * BK + (((s * 4 + lhi) ^ (row & 7)) * 8));
      }
#pragma unroll
      for (int j = 0; j < 4; ++j) {
        int row = wn + j * 16 + l15;
        bfr[j] = *(const bf16x8*)(Bls + row * BK + (((s * 4 + lhi) ^ (row & 7)) * 8));
      }
#pragma unroll
      for (int i = 0; i < 4; ++i)
#pragma unroll
        for (int j = 0; j < 4; ++j)
          acc[i][j] = __builtin_amdgcn_mfma_f32_16x16x32_bf16(af[i], bfr[j], acc[i][j], 0, 0, 0);
    }
    __syncthreads();
  }

  // epilogue: D layout col = lane&15, row = 4*(lane>>4)+r  [verified m89/m91]
  if constexpr (MODE == 0) {
#pragma unroll
    for (int i = 0; i < 4; ++i)
#pragma unroll
      for (int r = 0; r < 4; ++r) {
        int gr = tm + wm + i * 16 + 4 * lhi + r;
#pragma unroll
        for (int j = 0; j < 4; ++j) {
          int gc = tn + wn + j * 16 + l15;
          statef[(size_t)gr * N + gc] = acc[i][j][r];
        }
      }
  } else if constexpr (MODE == 1) {
#pragma unroll
    for (int i = 0; i < 4; ++i)
#pragma unroll
      for (int r = 0; r < 4; ++r) {
        int gr = tm + wm + i * 16 + 4 * lhi + r;
#pragma unroll
        for (int j = 0; j < 4; ++j) {
          int gc = tn + wn + j * 16 + l15;
          size_t idx = (size_t)gr * N + gc;
          float pre = acc[i][j][r] + addc[idx] + bias[gc];
          float old = statef[idx];
          float sg = sigm(old);
          float nv = old - SS * (sg * (1.0f - sg) * pre - old);
          statef[idx] = nv;
          sigb[idx] = f2bf(sigm(nv));
        }
      }
  } else {
#pragma unroll
    for (int j = 0; j < 4; ++j) {
      int gc = tn + wn + j * 16 + l15;
      float w2r[10];
#pragma unroll
      for (int k = 0; k < 10; ++k) w2r[k] = w2[gc * 10 + k];
      float bgc = bias[gc];
#pragma unroll
      for (int i = 0; i < 4; ++i)
#pragma unroll
        for (int r = 0; r < 4; ++r) {
          int gr = tm + wm + i * 16 + 4 * lhi + r;
          float extra = bgc;
#pragma unroll
          for (int k = 0; k < 10; ++k) extra += sig3[gr * 10 + k] * w2r[k];
          size_t idx = (size_t)gr * N + gc;
          float pre = acc[i][j][r] + extra;
          float old = statef[idx];
          float sg = sigm(old);
          float nv = old - SS * (sg * (1.0f - sg) * pre - old);
          statef[idx] = nv;
          sigb[idx] = f2bf(sigm(nv));
        }
    }
  }
}

// ---------------------------------------------------------------------------
// output-layer update: pre[m][n] = sum_k sig(s2_new[m][k]) * w2[k*10+n] + b2[n]
// 16 rows per block, 16 lanes per row, shuffle-reduce within 16-lane groups.
// ---------------------------------------------------------------------------
__global__ void k_out(const u16* __restrict__ sigs2b, const float* __restrict__ w2,
                      const float* __restrict__ b2, float* __restrict__ s3f,
                      float* __restrict__ sigs3f, float* __restrict__ outOrNull) {
  int tid = threadIdx.x;
  int r = tid >> 4, l16 = tid & 15;
  int row = blockIdx.x * 16 + r;
  float acc[10] = {};
  const u16* arow = sigs2b + (size_t)row * 2048;
  for (int k = l16; k < 2048; k += 16) {
    float a = bf2f(arow[k]);
    const float* wr = w2 + (size_t)k * 10;
#pragma unroll
    for (int n = 0; n < 10; ++n) acc[n] += a * wr[n];
  }
#pragma unroll
  for (int m = 1; m < 16; m <<= 1)
#pragma unroll
    for (int n = 0; n < 10; ++n) acc[n] += __shfl_xor(acc[n], m, 64);
  if (l16 < 10) {
    float pre = 0.0f;
#pragma unroll
    for (int n = 0; n < 10; ++n)
      if (l16 == n) pre = acc[n];
    pre += b2[l16];
    size_t idx = (size_t)row * 10 + l16;
    float old = s3f[idx];
    float sg = sigm(old);
    float nv = old - SS * (sg * (1.0f - sg) * pre - old);
    s3f[idx] = nv;
    sigs3f[idx] = sigm(nv);
    if (outOrNull) outOrNull[idx] = nv;
  }
}

// ---------------------------------------------------------------------------
extern "C" void kernel_launch(void* const* d_in, const int* in_sizes, int n_in,
                              void* d_out, int out_size, void* d_ws, size_t ws_size,
                              hipStream_t stream) {
  const float* x  = (const float*)d_in[0];
  const float* w0 = (const float*)d_in[1];  // 1024 x 2048
  const float* w1 = (const float*)d_in[2];  // 2048 x 2048
  const float* w2 = (const float*)d_in[3];  // 2048 x 10
  const float* b0 = (const float*)d_in[4];
  const float* b1 = (const float*)d_in[5];
  const float* b2 = (const float*)d_in[6];
  const float* s1 = (const float*)d_in[7];
  const float* s2 = (const float*)d_in[8];
  const float* s3 = (const float*)d_in[9];
  float* out = (float*)d_out;

  uint8_t* p = (uint8_t*)d_ws;
  auto alloc = [&](size_t bytes) {
    uint8_t* r = p;
    p += (bytes + 255) & ~(size_t)255;
    return r;
  };
  float* s1f    = (float*)alloc(4096ull * 2048 * 4);
  float* s2f    = (float*)alloc(4096ull * 2048 * 4);
  float* sigxw0 = (float*)alloc(4096ull * 2048 * 4);  // sig(x)@w0, loop-invariant
  u16*   sigs1b = (u16*)alloc(4096ull * 2048 * 2);
  u16*   sigs2b = (u16*)alloc(4096ull * 2048 * 2);
  u16*   sigxb  = (u16*)alloc(4096ull * 1024 * 2);
  u16*   w1b    = (u16*)alloc(2048ull * 2048 * 2);    // Bt-layout for B = w1^T
  u16*   w1tb   = (u16*)alloc(2048ull * 2048 * 2);    // Bt-layout for B = w1
  u16*   w0tb   = (u16*)alloc(2048ull * 1024 * 2);    // Bt-layout for B = w0
  float* s3f    = (float*)alloc(4096ull * 10 * 4);
  float* sigs3f = (float*)alloc(4096ull * 10 * 4);
  (void)ws_size; (void)in_sizes; (void)n_in; (void)out_size;

  auto grid = [](int n) { int g = (n + 255) / 256; return g > 2048 ? 2048 : g; };

  // one-time prep (re-done every call: poison-safe, deterministic)
  k_prep<<<grid(4096 * 1024), 256, 0, stream>>>(x, nullptr, nullptr, sigxb, nullptr, 4096 * 1024);
  k_prep<<<grid(2048 * 2048), 256, 0, stream>>>(w1, nullptr, nullptr, nullptr, w1b, 2048 * 2048);
  k_prep<<<grid(4096 * 2048), 256, 0, stream>>>(s1, s1f, nullptr, nullptr, nullptr, 4096 * 2048);
  k_prep<<<grid(4096 * 2048), 256, 0, stream>>>(s2, s2f, nullptr, sigs2b, nullptr, 4096 * 2048);
  k_prep<<<grid(40960), 256, 0, stream>>>(s3, s3f, sigs3f, nullptr, nullptr, 40960);
  k_transpose_bf16<<<dim3(1024 / 32, 2048 / 32), 256, 0, stream>>>(w0, w0tb, 1024, 2048);
  k_transpose_bf16<<<dim3(2048 / 32, 2048 / 32), 256, 0, stream>>>(w1, w1tb, 2048, 2048);

  // sigxw0 = sig(x) @ w0   (M=4096, N=2048, K=1024)
  k_gemm<0><<<512, 256, 0, stream>>>(sigxb, w0tb, 4096, 2048, 1024,
                                     nullptr, nullptr, nullptr, nullptr, sigxw0, nullptr);

  for (int t = 0; t < 20; ++t) {
    // s1 update: pre = sigxw0 + sig(s2)@w1^T + b0
    k_gemm<1><<<512, 256, 0, stream>>>(sigs2b, w1b, 4096, 2048, 2048,
                                       sigxw0, b0, nullptr, nullptr, s1f, sigs1b);
    // s2 update: pre = sig(s1_new)@w1 + sig(s3)@w2^T + b1
    k_gemm<2><<<512, 256, 0, stream>>>(sigs1b, w1tb, 4096, 2048, 2048,
                                       nullptr, b1, sigs3f, w2, s2f, sigs2b);
    // s3 update: pre = sig(s2_new)@w2 + b2
    k_out<<<256, 256, 0, stream>>>(sigs2b, w2, b2, s3f, sigs3f, (t == 19) ? out : nullptr);
  }
}

// Round 2
// 2909.692 us; speedup vs baseline: 3.4192x; 3.4192x over previous
//
#include <hip/hip_runtime.h>
#include <cstdint>
#include <cstddef>

using u16 = unsigned short;
using u32 = unsigned int;

typedef __bf16 bf16x8 __attribute__((ext_vector_type(8)));
typedef float f32x4 __attribute__((ext_vector_type(4)));
typedef u16 u16x4 __attribute__((ext_vector_type(4)));

#define DEV __device__ __forceinline__

constexpr float SS = 0.1f / 20.0f;  // STEP_SIZE = DT / N_STEPS

DEV float sigm(float x) { return 1.0f / (1.0f + __expf(-x)); }

DEV u16 f2bf(float f) {  // round-to-nearest-even f32 -> bf16
  union { float f; u32 u; } v; v.f = f;
  u32 r = v.u + 0x7FFFu + ((v.u >> 16) & 1u);
  return (u16)(r >> 16);
}
DEV float bf2f(u16 h) {
  union { u32 u; float f; } v; v.u = ((u32)h) << 16;
  return v.f;
}

// ---------------------------------------------------------------------------
// prep: optional copy / sigmoid(f32) / sigmoid(bf16) / raw bf16 convert
// ---------------------------------------------------------------------------
__global__ void k_prep(const float* __restrict__ in, float* __restrict__ fcopy,
                       float* __restrict__ sigf32, u16* __restrict__ sigb,
                       u16* __restrict__ rawb, int n) {
  int stride = gridDim.x * blockDim.x;
  for (int i = blockIdx.x * blockDim.x + threadIdx.x; i < n; i += stride) {
    float v = in[i];
    if (fcopy) fcopy[i] = v;
    if (rawb) rawb[i] = f2bf(v);
    if (sigf32 || sigb) {
      float s = sigm(v);
      if (sigf32) sigf32[i] = s;
      if (sigb) sigb[i] = f2bf(s);
    }
  }
}

// out[n][k] = bf16(in[k][n]);  in: K x N f32, K,N multiples of 32
__global__ void k_transpose_bf16(const float* __restrict__ in, u16* __restrict__ out,
                                 int K, int N) {
  __shared__ float tile[32][33];
  int kb = blockIdx.x * 32, nb = blockIdx.y * 32;
  int tx = threadIdx.x & 31, ty = threadIdx.x >> 5;  // 256 threads: 32x8
#pragma unroll
  for (int i = 0; i < 4; ++i)
    tile[ty + 8 * i][tx] = in[(size_t)(kb + ty + 8 * i) * N + nb + tx];
  __syncthreads();
#pragma unroll
  for (int i = 0; i < 4; ++i)
    out[(size_t)(nb + ty + 8 * i) * K + kb + tx] = f2bf(tile[tx][ty + 8 * i]);
}

// ---------------------------------------------------------------------------
// GEMM: C = A(MxK, bf16 row-major) * Bt^T  (Bt = N x K bf16 row-major).
// 128x128 tile, BK=64, 4 waves each 64x64, 16x16x32 MFMA, operands SWAPPED
// (mfma(b,a)) so each lane's 4 acc regs are 4 CONSECUTIVE C-columns ->
// float4/u16x4 vectorized epilogue. LDS XOR-swizzled both-sides (rule #21).
// Grid is always 32x16 tiles = 512 blocks; XCD-aware 2D chunking: xcd=b%8
// owns an 8x8 tile region (A fetched 2x, B 4x instead of 16x/32x).
// MODE 0: addcb[m][n] = bf16(acc + bias[n])            (loop-invariant term)
// MODE 1: pre = acc + bf2f(addcb[m][n]); state update -> statef, sigb
// MODE 2: pre = acc + bias[n] + sum_k sig3[m][k]*w2[n*10+k]; update state
// ---------------------------------------------------------------------------
template <int MODE>
__global__ void k_gemm(const u16* __restrict__ A, const u16* __restrict__ Bt,
                       int M, int N, int K,
                       const u16* __restrict__ addcb, const float* __restrict__ bias,
                       const float* __restrict__ sig3, const float* __restrict__ w2,
                       float* __restrict__ statef, u16* __restrict__ sigb) {
  constexpr int BM = 128, BN = 128, BK = 64;
  __shared__ __align__(16) u16 Als[BM * BK];
  __shared__ __align__(16) u16 Bls[BN * BK];
  // XCD-aware block -> (tile-row, tile-col); grid assumed 32x16 (512 blocks)
  int b = blockIdx.x;
  int xcd = b & 7, slot = b >> 3;
  int tm = ((((xcd >> 1) << 3) | (slot >> 3))) * BM;  // 0..31
  int tn = ((((xcd & 1) << 3) | (slot & 7))) * BN;    // 0..15
  int tid = threadIdx.x;
  int lane = tid & 63, wid = tid >> 6;
  int l15 = lane & 15, lhi = lane >> 4;
  int wm = (wid >> 1) * 64, wn = (wid & 1) * 64;

  f32x4 acc[4][4] = {};

  const u16* Ag = A + (size_t)tm * K;
  const u16* Bg = Bt + (size_t)tn * K;

  for (int k0 = 0; k0 < K; k0 += BK) {
#pragma unroll
    for (int rd = 0; rd < 4; ++rd) {
      int S = rd * 256 + tid;              // 16B slot index, linear in LDS
      int row = S >> 3;                    // 8 slots (128B) per 64-elem row
      int cs = ((S & 7) ^ (row & 7)) * 8;  // pre-swizzled global column
      __builtin_amdgcn_global_load_lds(
          (const __attribute__((address_space(1))) u32*)(Ag + (size_t)row * K + k0 + cs),
          (__attribute__((address_space(3))) u32*)(Als + S * 8), 16, 0, 0);
      __builtin_amdgcn_global_load_lds(
          (const __attribute__((address_space(1))) u32*)(Bg + (size_t)row * K + k0 + cs),
          (__attribute__((address_space(3))) u32*)(Bls + S * 8), 16, 0, 0);
    }
    __syncthreads();
#pragma unroll
    for (int s = 0; s < 2; ++s) {
      bf16x8 af[4], bfr[4];
#pragma unroll
      for (int i = 0; i < 4; ++i) {
        int row = wm + i * 16 + l15;
        af[i] = *(const bf16x8*)(Als + row * BK + (((s * 4 + lhi) ^ (row & 7)) * 8));
      }
#pragma unroll
      for (int j = 0; j < 4; ++j) {
        int row = wn + j * 16 + l15;
        bfr[j] = *(const bf16x8*)(Bls + row * BK + (((s * 4 + lhi) ^ (row & 7)) * 8));
      }
#pragma unroll
      for (int i = 0; i < 4; ++i)
#pragma unroll
        for (int j = 0; j < 4; ++j)  // SWAPPED operands: lane = C-row, regs = 4 C-cols
          acc[i][j] = __builtin_amdgcn_mfma_f32_16x16x32_bf16(bfr[j], af[i], acc[i][j], 0, 0, 0);
    }
    __syncthreads();
  }

  // Swapped D layout: acc[i][j][rr] = C[tm+wm+i*16+l15][tn+wn+j*16+4*lhi+rr]
  if constexpr (MODE == 0) {
#pragma unroll
    for (int i = 0; i < 4; ++i) {
      int gr = tm + wm + i * 16 + l15;
#pragma unroll
      for (int j = 0; j < 4; ++j) {
        int gc0 = tn + wn + j * 16 + 4 * lhi;
        u16x4 sb;
#pragma unroll
        for (int rr = 0; rr < 4; ++rr) sb[rr] = f2bf(acc[i][j][rr] + bias[gc0 + rr]);
        *(u16x4*)(sigb + (size_t)gr * N + gc0) = sb;
      }
    }
  } else if constexpr (MODE == 1) {
#pragma unroll
    for (int i = 0; i < 4; ++i) {
      int gr = tm + wm + i * 16 + l15;
#pragma unroll
      for (int j = 0; j < 4; ++j) {
        int gc0 = tn + wn + j * 16 + 4 * lhi;
        size_t idx = (size_t)gr * N + gc0;
        u16x4 ab = *(const u16x4*)(addcb + idx);
        f32x4 old = *(const f32x4*)(statef + idx);
        f32x4 nv; u16x4 sb;
#pragma unroll
        for (int rr = 0; rr < 4; ++rr) {
          float pre = acc[i][j][rr] + bf2f(ab[rr]);
          float o = old[rr];
          float sg = sigm(o);
          float n = o - SS * (sg * (1.0f - sg) * pre - o);
          nv[rr] = n; sb[rr] = f2bf(sigm(n));
        }
        *(f32x4*)(statef + idx) = nv;
        *(u16x4*)(sigb + idx) = sb;
      }
    }
  } else {
    float s3v[4][10];
#pragma unroll
    for (int i = 0; i < 4; ++i) {
      int gr = tm + wm + i * 16 + l15;
#pragma unroll
      for (int k = 0; k < 10; ++k) s3v[i][k] = sig3[gr * 10 + k];
    }
#pragma unroll
    for (int j = 0; j < 4; ++j) {
      int gc0 = tn + wn + j * 16 + 4 * lhi;
      float wv[4][10]; f32x4 bb;
#pragma unroll
      for (int rr = 0; rr < 4; ++rr) {
        bb[rr] = bias[gc0 + rr];
#pragma unroll
        for (int k = 0; k < 10; ++k) wv[rr][k] = w2[(gc0 + rr) * 10 + k];
      }
#pragma unroll
      for (int i = 0; i < 4; ++i) {
        int gr = tm + wm + i * 16 + l15;
        size_t idx = (size_t)gr * N + gc0;
        f32x4 old = *(const f32x4*)(statef + idx);
        f32x4 nv; u16x4 sb;
#pragma unroll
        for (int rr = 0; rr < 4; ++rr) {
          float ex = bb[rr];
#pragma unroll
          for (int k = 0; k < 10; ++k) ex += s3v[i][k] * wv[rr][k];
          float pre = acc[i][j][rr] + ex;
          float o = old[rr];
          float sg = sigm(o);
          float n = o - SS * (sg * (1.0f - sg) * pre - o);
          nv[rr] = n; sb[rr] = f2bf(sigm(n));
        }
        *(f32x4*)(statef + idx) = nv;
        *(u16x4*)(sigb + idx) = sb;
      }
    }
  }
}

// ---------------------------------------------------------------------------
// output-layer update: pre[m][n] = sum_k sig(s2_new[m][k]) * w2[k*10+n] + b2[n]
// 16 rows per block, 16 lanes per row, bf16x8 vector loads, shuffle-reduce.
// ---------------------------------------------------------------------------
__global__ void k_out(const u16* __restrict__ sigs2b, const float* __restrict__ w2,
                      const float* __restrict__ b2, float* __restrict__ s3f,
                      float* __restrict__ sigs3f, float* __restrict__ outOrNull) {
  int tid = threadIdx.x;
  int r = tid >> 4, l16 = tid & 15;
  int row = blockIdx.x * 16 + r;
  float acc[10] = {};
  const u16* arow = sigs2b + (size_t)row * 2048;
  for (int kb = l16; kb < 256; kb += 16) {  // 8 u16 per chunk, 16B coalesced
    u16x4 v0 = *(const u16x4*)(arow + kb * 8);
    u16x4 v1 = *(const u16x4*)(arow + kb * 8 + 4);
    float a[8];
#pragma unroll
    for (int e = 0; e < 4; ++e) { a[e] = bf2f(v0[e]); a[e + 4] = bf2f(v1[e]); }
    const float* wr = w2 + (size_t)kb * 80;
#pragma unroll
    for (int e = 0; e < 8; ++e)
#pragma unroll
      for (int n = 0; n < 10; ++n) acc[n] += a[e] * wr[e * 10 + n];
  }
#pragma unroll
  for (int m = 1; m < 16; m <<= 1)
#pragma unroll
    for (int n = 0; n < 10; ++n) acc[n] += __shfl_xor(acc[n], m, 64);
  if (l16 < 10) {
    float pre = 0.0f;
#pragma unroll
    for (int n = 0; n < 10; ++n)
      if (l16 == n) pre = acc[n];
    pre += b2[l16];
    size_t idx = (size_t)row * 10 + l16;
    float old = s3f[idx];
    float sg = sigm(old);
    float nv = old - SS * (sg * (1.0f - sg) * pre - old);
    s3f[idx] = nv;
    sigs3f[idx] = sigm(nv);
    if (outOrNull) outOrNull[idx] = nv;
  }
}

// ---------------------------------------------------------------------------
extern "C" void kernel_launch(void* const* d_in, const int* in_sizes, int n_in,
                              void* d_out, int out_size, void* d_ws, size_t ws_size,
                              hipStream_t stream) {
  const float* x  = (const float*)d_in[0];
  const float* w0 = (const float*)d_in[1];  // 1024 x 2048
  const float* w1 = (const float*)d_in[2];  // 2048 x 2048
  const float* w2 = (const float*)d_in[3];  // 2048 x 10
  const float* b0 = (const float*)d_in[4];
  const float* b1 = (const float*)d_in[5];
  const float* b2 = (const float*)d_in[6];
  const float* s1 = (const float*)d_in[7];
  const float* s2 = (const float*)d_in[8];
  const float* s3 = (const float*)d_in[9];
  float* out = (float*)d_out;

  uint8_t* p = (uint8_t*)d_ws;
  auto alloc = [&](size_t bytes) {
    uint8_t* r = p;
    p += (bytes + 255) & ~(size_t)255;
    return r;
  };
  float* s1f    = (float*)alloc(4096ull * 2048 * 4);
  float* s2f    = (float*)alloc(4096ull * 2048 * 4);
  u16*   addcb  = (u16*)alloc(4096ull * 2048 * 2);    // bf16(sig(x)@w0 + b0)
  u16*   sigs1b = (u16*)alloc(4096ull * 2048 * 2);
  u16*   sigs2b = (u16*)alloc(4096ull * 2048 * 2);
  u16*   sigxb  = (u16*)alloc(4096ull * 1024 * 2);
  u16*   w1b    = (u16*)alloc(2048ull * 2048 * 2);    // Bt-layout for B = w1^T
  u16*   w1tb   = (u16*)alloc(2048ull * 2048 * 2);    // Bt-layout for B = w1
  u16*   w0tb   = (u16*)alloc(2048ull * 1024 * 2);    // Bt-layout for B = w0
  float* s3f    = (float*)alloc(4096ull * 10 * 4);
  float* sigs3f = (float*)alloc(4096ull * 10 * 4);
  (void)ws_size; (void)in_sizes; (void)n_in; (void)out_size;

  auto grid = [](int n) { int g = (n + 255) / 256; return g > 2048 ? 2048 : g; };

  // one-time prep (re-done every call: poison-safe, deterministic)
  k_prep<<<grid(4096 * 1024), 256, 0, stream>>>(x, nullptr, nullptr, sigxb, nullptr, 4096 * 1024);
  k_prep<<<grid(2048 * 2048), 256, 0, stream>>>(w1, nullptr, nullptr, nullptr, w1b, 2048 * 2048);
  k_prep<<<grid(4096 * 2048), 256, 0, stream>>>(s1, s1f, nullptr, nullptr, nullptr, 4096 * 2048);
  k_prep<<<grid(4096 * 2048), 256, 0, stream>>>(s2, s2f, nullptr, sigs2b, nullptr, 4096 * 2048);
  k_prep<<<grid(40960), 256, 0, stream>>>(s3, s3f, sigs3f, nullptr, nullptr, 40960);
  k_transpose_bf16<<<dim3(1024 / 32, 2048 / 32), 256, 0, stream>>>(w0, w0tb, 1024, 2048);
  k_transpose_bf16<<<dim3(2048 / 32, 2048 / 32), 256, 0, stream>>>(w1, w1tb, 2048, 2048);

  // addcb = bf16(sig(x) @ w0 + b0)   (M=4096, N=2048, K=1024) — loop-invariant
  k_gemm<0><<<512, 256, 0, stream>>>(sigxb, w0tb, 4096, 2048, 1024,
                                     nullptr, b0, nullptr, nullptr, nullptr, addcb);

  for (int t = 0; t < 20; ++t) {
    // s1 update: pre = (sigxw0 + b0) + sig(s2)@w1^T
    k_gemm<1><<<512, 256, 0, stream>>>(sigs2b, w1b, 4096, 2048, 2048,
                                       addcb, nullptr, nullptr, nullptr, s1f, sigs1b);
    // s2 update: pre = sig(s1_new)@w1 + sig(s3)@w2^T + b1
    k_gemm<2><<<512, 256, 0, stream>>>(sigs1b, w1tb, 4096, 2048, 2048,
                                       nullptr, b1, sigs3f, w2, s2f, sigs2b);
    // s3 update: pre = sig(s2_new)@w2 + b2
    k_out<<<256, 256, 0, stream>>>(sigs2b, w2, b2, s3f, sigs3f, (t == 19) ? out : nullptr);
  }
}

// Round 3
// 2678.398 us; speedup vs baseline: 3.7144x; 1.0864x over previous
//
#include <hip/hip_runtime.h>
#include <cstdint>
#include <cstddef>

using u16 = unsigned short;
using u32 = unsigned int;

typedef __bf16 bf16x8 __attribute__((ext_vector_type(8)));
typedef float f32x4 __attribute__((ext_vector_type(4)));
typedef u16 u16x4 __attribute__((ext_vector_type(4)));

#define DEV __device__ __forceinline__

constexpr float SS = 0.1f / 20.0f;  // STEP_SIZE = DT / N_STEPS

DEV float sigm(float x) { return 1.0f / (1.0f + __expf(-x)); }

DEV u16 f2bf(float f) {  // round-to-nearest-even f32 -> bf16
  union { float f; u32 u; } v; v.f = f;
  u32 r = v.u + 0x7FFFu + ((v.u >> 16) & 1u);
  return (u16)(r >> 16);
}
DEV float bf2f(u16 h) {
  union { u32 u; float f; } v; v.u = ((u32)h) << 16;
  return v.f;
}

// ---------------------------------------------------------------------------
// prep: optional copy / sigmoid(f32) / sigmoid(bf16) / raw bf16 convert
// ---------------------------------------------------------------------------
__global__ void k_prep(const float* __restrict__ in, float* __restrict__ fcopy,
                       float* __restrict__ sigf32, u16* __restrict__ sigb,
                       u16* __restrict__ rawb, int n) {
  int stride = gridDim.x * blockDim.x;
  for (int i = blockIdx.x * blockDim.x + threadIdx.x; i < n; i += stride) {
    float v = in[i];
    if (fcopy) fcopy[i] = v;
    if (rawb) rawb[i] = f2bf(v);
    if (sigf32 || sigb) {
      float s = sigm(v);
      if (sigf32) sigf32[i] = s;
      if (sigb) sigb[i] = f2bf(s);
    }
  }
}

// out[n][k] = bf16(in[k][n]);  in: K x N f32, K,N multiples of 32
__global__ void k_transpose_bf16(const float* __restrict__ in, u16* __restrict__ out,
                                 int K, int N) {
  __shared__ float tile[32][33];
  int kb = blockIdx.x * 32, nb = blockIdx.y * 32;
  int tx = threadIdx.x & 31, ty = threadIdx.x >> 5;  // 256 threads: 32x8
#pragma unroll
  for (int i = 0; i < 4; ++i)
    tile[ty + 8 * i][tx] = in[(size_t)(kb + ty + 8 * i) * N + nb + tx];
  __syncthreads();
#pragma unroll
  for (int i = 0; i < 4; ++i)
    out[(size_t)(nb + ty + 8 * i) * K + kb + tx] = f2bf(tile[tx][ty + 8 * i]);
}

// ---------------------------------------------------------------------------
// GEMM: C = A(MxK, bf16 row-major) * Bt^T  (Bt = N x K bf16 row-major).
// 128x128 tile, BK=64, 4 waves each 64x64, 16x16x32 MFMA with SWAPPED
// operands (mfma(b,a)): lane = C-row, 4 acc regs = 4 consecutive C-cols ->
// float4/u16x4 epilogue. LDS XOR-swizzled both-sides (rule #21).
// 2-phase software pipeline (T3 minimum recipe): double-buffered LDS,
// stage(next) issued BEFORE compute(cur), single raw s_barrier per K-step
// with explicit vmcnt(0)+lgkmcnt(0) drain AFTER compute. nt must be even.
// XCD-aware 2D chunking: grid fixed 32x16 tiles = 512 blocks; xcd=b%8 owns
// an 8x8 tile region.
// MODE 0: sigb[m][n] = bf16(acc + bias[n])             (loop-invariant term)
// MODE 1: pre = acc + bf2f(addcb[m][n]); state update -> statef, sigb
// MODE 2: pre = acc + bias[n] + sum_k sig3[m][k]*w2[n*10+k]; update state
// ---------------------------------------------------------------------------
template <int MODE>
__launch_bounds__(256)
__global__ void k_gemm(const u16* __restrict__ A, const u16* __restrict__ Bt,
                       int M, int N, int K,
                       const u16* __restrict__ addcb, const float* __restrict__ bias,
                       const float* __restrict__ sig3, const float* __restrict__ w2,
                       float* __restrict__ statef, u16* __restrict__ sigb) {
  constexpr int BM = 128, BN = 128, BK = 64;
  __shared__ __align__(16) u16 Als[2][BM * BK];
  __shared__ __align__(16) u16 Bls[2][BN * BK];
  int b = blockIdx.x;
  int xcd = b & 7, slot = b >> 3;
  int tm = ((((xcd >> 1) << 3) | (slot >> 3))) * BM;  // 0..31
  int tn = ((((xcd & 1) << 3) | (slot & 7))) * BN;    // 0..15
  int tid = threadIdx.x;
  int lane = tid & 63, wid = tid >> 6;
  int l15 = lane & 15, lhi = lane >> 4;
  int wm = (wid >> 1) * 64, wn = (wid & 1) * 64;

  const u16* Ag = A + (size_t)tm * K;
  const u16* Bg = Bt + (size_t)tn * K;

  f32x4 acc[4][4] = {};

  auto stage = [&](int buf, int k0) {
#pragma unroll
    for (int rd = 0; rd < 4; ++rd) {
      int S = rd * 256 + tid;              // 16B slot index, linear in LDS
      int row = S >> 3;                    // 8 slots (128B) per 64-elem row
      int cs = ((S & 7) ^ (row & 7)) * 8;  // pre-swizzled global column
      __builtin_amdgcn_global_load_lds(
          (const __attribute__((address_space(1))) u32*)(Ag + (size_t)row * K + k0 + cs),
          (__attribute__((address_space(3))) u32*)(&Als[buf][0] + S * 8), 16, 0, 0);
      __builtin_amdgcn_global_load_lds(
          (const __attribute__((address_space(1))) u32*)(Bg + (size_t)row * K + k0 + cs),
          (__attribute__((address_space(3))) u32*)(&Bls[buf][0] + S * 8), 16, 0, 0);
    }
  };

  auto compute = [&](int buf) {
#pragma unroll
    for (int s = 0; s < 2; ++s) {
      bf16x8 af[4], bfr[4];
#pragma unroll
      for (int i = 0; i < 4; ++i) {
        int row = wm + i * 16 + l15;
        af[i] = *(const bf16x8*)(&Als[buf][0] + row * BK + (((s * 4 + lhi) ^ (row & 7)) * 8));
      }
#pragma unroll
      for (int j = 0; j < 4; ++j) {
        int row = wn + j * 16 + l15;
        bfr[j] = *(const bf16x8*)(&Bls[buf][0] + row * BK + (((s * 4 + lhi) ^ (row & 7)) * 8));
      }
#pragma unroll
      for (int i = 0; i < 4; ++i)
#pragma unroll
        for (int j = 0; j < 4; ++j)  // SWAPPED operands
          acc[i][j] = __builtin_amdgcn_mfma_f32_16x16x32_bf16(bfr[j], af[i], acc[i][j], 0, 0, 0);
    }
  };

  // --- 2-phase pipeline, 2 K-steps per loop iter (static buffer indices) ---
  const int nt = K / BK;  // 16 or 32, always even
  stage(0, 0);
  asm volatile("s_waitcnt vmcnt(0)" ::: "memory");
  __builtin_amdgcn_s_barrier();
  asm volatile("" ::: "memory");
  int t = 0;
  for (; t + 2 < nt; t += 2) {
    stage(1, (t + 1) * BK);
    compute(0);
    asm volatile("s_waitcnt vmcnt(0) lgkmcnt(0)" ::: "memory");
    __builtin_amdgcn_s_barrier();
    asm volatile("" ::: "memory");
    stage(0, (t + 2) * BK);
    compute(1);
    asm volatile("s_waitcnt vmcnt(0) lgkmcnt(0)" ::: "memory");
    __builtin_amdgcn_s_barrier();
    asm volatile("" ::: "memory");
  }
  // t == nt-2
  stage(1, (nt - 1) * BK);
  compute(0);
  asm volatile("s_waitcnt vmcnt(0) lgkmcnt(0)" ::: "memory");
  __builtin_amdgcn_s_barrier();
  asm volatile("" ::: "memory");
  compute(1);

  // Swapped D layout: acc[i][j][rr] = C[tm+wm+i*16+l15][tn+wn+j*16+4*lhi+rr]
  if constexpr (MODE == 0) {
#pragma unroll
    for (int i = 0; i < 4; ++i) {
      int gr = tm + wm + i * 16 + l15;
#pragma unroll
      for (int j = 0; j < 4; ++j) {
        int gc0 = tn + wn + j * 16 + 4 * lhi;
        u16x4 sb;
#pragma unroll
        for (int rr = 0; rr < 4; ++rr) sb[rr] = f2bf(acc[i][j][rr] + bias[gc0 + rr]);
        *(u16x4*)(sigb + (size_t)gr * N + gc0) = sb;
      }
    }
  } else if constexpr (MODE == 1) {
#pragma unroll
    for (int i = 0; i < 4; ++i) {
      int gr = tm + wm + i * 16 + l15;
#pragma unroll
      for (int j = 0; j < 4; ++j) {
        int gc0 = tn + wn + j * 16 + 4 * lhi;
        size_t idx = (size_t)gr * N + gc0;
        u16x4 ab = *(const u16x4*)(addcb + idx);
        f32x4 old = *(const f32x4*)(statef + idx);
        f32x4 nv; u16x4 sb;
#pragma unroll
        for (int rr = 0; rr < 4; ++rr) {
          float pre = acc[i][j][rr] + bf2f(ab[rr]);
          float o = old[rr];
          float sg = sigm(o);
          float n = o - SS * (sg * (1.0f - sg) * pre - o);
          nv[rr] = n; sb[rr] = f2bf(sigm(n));
        }
        *(f32x4*)(statef + idx) = nv;
        *(u16x4*)(sigb + idx) = sb;
      }
    }
  } else {
    float s3v[4][10];
#pragma unroll
    for (int i = 0; i < 4; ++i) {
      int gr = tm + wm + i * 16 + l15;
#pragma unroll
      for (int k = 0; k < 10; ++k) s3v[i][k] = sig3[gr * 10 + k];
    }
#pragma unroll
    for (int j = 0; j < 4; ++j) {
      int gc0 = tn + wn + j * 16 + 4 * lhi;
      float wv[4][10]; f32x4 bb;
#pragma unroll
      for (int rr = 0; rr < 4; ++rr) {
        bb[rr] = bias[gc0 + rr];
#pragma unroll
        for (int k = 0; k < 10; ++k) wv[rr][k] = w2[(gc0 + rr) * 10 + k];
      }
#pragma unroll
      for (int i = 0; i < 4; ++i) {
        int gr = tm + wm + i * 16 + l15;
        size_t idx = (size_t)gr * N + gc0;
        f32x4 old = *(const f32x4*)(statef + idx);
        f32x4 nv; u16x4 sb;
#pragma unroll
        for (int rr = 0; rr < 4; ++rr) {
          float ex = bb[rr];
#pragma unroll
          for (int k = 0; k < 10; ++k) ex += s3v[i][k] * wv[rr][k];
          float pre = acc[i][j][rr] + ex;
          float o = old[rr];
          float sg = sigm(o);
          float n = o - SS * (sg * (1.0f - sg) * pre - o);
          nv[rr] = n; sb[rr] = f2bf(sigm(n));
        }
        *(f32x4*)(statef + idx) = nv;
        *(u16x4*)(sigb + idx) = sb;
      }
    }
  }
}

// ---------------------------------------------------------------------------
// output-layer update: pre[m][n] = sum_k sig(s2_new[m][k]) * w2[k*10+n] + b2[n]
// 16 rows per block, 16 lanes per row, bf16x8 vector loads, shuffle-reduce.
// ---------------------------------------------------------------------------
__global__ void k_out(const u16* __restrict__ sigs2b, const float* __restrict__ w2,
                      const float* __restrict__ b2, float* __restrict__ s3f,
                      float* __restrict__ sigs3f, float* __restrict__ outOrNull) {
  int tid = threadIdx.x;
  int r = tid >> 4, l16 = tid & 15;
  int row = blockIdx.x * 16 + r;
  float acc[10] = {};
  const u16* arow = sigs2b + (size_t)row * 2048;
  for (int kb = l16; kb < 256; kb += 16) {  // 8 u16 per chunk, 16B coalesced
    u16x4 v0 = *(const u16x4*)(arow + kb * 8);
    u16x4 v1 = *(const u16x4*)(arow + kb * 8 + 4);
    float a[8];
#pragma unroll
    for (int e = 0; e < 4; ++e) { a[e] = bf2f(v0[e]); a[e + 4] = bf2f(v1[e]); }
    const float* wr = w2 + (size_t)kb * 80;
#pragma unroll
    for (int e = 0; e < 8; ++e)
#pragma unroll
      for (int n = 0; n < 10; ++n) acc[n] += a[e] * wr[e * 10 + n];
  }
#pragma unroll
  for (int m = 1; m < 16; m <<= 1)
#pragma unroll
    for (int n = 0; n < 10; ++n) acc[n] += __shfl_xor(acc[n], m, 64);
  if (l16 < 10) {
    float pre = 0.0f;
#pragma unroll
    for (int n = 0; n < 10; ++n)
      if (l16 == n) pre = acc[n];
    pre += b2[l16];
    size_t idx = (size_t)row * 10 + l16;
    float old = s3f[idx];
    float sg = sigm(old);
    float nv = old - SS * (sg * (1.0f - sg) * pre - old);
    s3f[idx] = nv;
    sigs3f[idx] = sigm(nv);
    if (outOrNull) outOrNull[idx] = nv;
  }
}

// ---------------------------------------------------------------------------
extern "C" void kernel_launch(void* const* d_in, const int* in_sizes, int n_in,
                              void* d_out, int out_size, void* d_ws, size_t ws_size,
                              hipStream_t stream) {
  const float* x  = (const float*)d_in[0];
  const float* w0 = (const float*)d_in[1];  // 1024 x 2048
  const float* w1 = (const float*)d_in[2];  // 2048 x 2048
  const float* w2 = (const float*)d_in[3];  // 2048 x 10
  const float* b0 = (const float*)d_in[4];
  const float* b1 = (const float*)d_in[5];
  const float* b2 = (const float*)d_in[6];
  const float* s1 = (const float*)d_in[7];
  const float* s2 = (const float*)d_in[8];
  const float* s3 = (const float*)d_in[9];
  float* out = (float*)d_out;

  uint8_t* p = (uint8_t*)d_ws;
  auto alloc = [&](size_t bytes) {
    uint8_t* r = p;
    p += (bytes + 255) & ~(size_t)255;
    return r;
  };
  float* s1f    = (float*)alloc(4096ull * 2048 * 4);
  float* s2f    = (float*)alloc(4096ull * 2048 * 4);
  u16*   addcb  = (u16*)alloc(4096ull * 2048 * 2);    // bf16(sig(x)@w0 + b0)
  u16*   sigs1b = (u16*)alloc(4096ull * 2048 * 2);
  u16*   sigs2b = (u16*)alloc(4096ull * 2048 * 2);
  u16*   sigxb  = (u16*)alloc(4096ull * 1024 * 2);
  u16*   w1b    = (u16*)alloc(2048ull * 2048 * 2);    // Bt-layout for B = w1^T
  u16*   w1tb   = (u16*)alloc(2048ull * 2048 * 2);    // Bt-layout for B = w1
  u16*   w0tb   = (u16*)alloc(2048ull * 1024 * 2);    // Bt-layout for B = w0
  float* s3f    = (float*)alloc(4096ull * 10 * 4);
  float* sigs3f = (float*)alloc(4096ull * 10 * 4);
  (void)ws_size; (void)in_sizes; (void)n_in; (void)out_size;

  auto grid = [](int n) { int g = (n + 255) / 256; return g > 2048 ? 2048 : g; };

  // one-time prep (re-done every call: poison-safe, deterministic)
  k_prep<<<grid(4096 * 1024), 256, 0, stream>>>(x, nullptr, nullptr, sigxb, nullptr, 4096 * 1024);
  k_prep<<<grid(2048 * 2048), 256, 0, stream>>>(w1, nullptr, nullptr, nullptr, w1b, 2048 * 2048);
  k_prep<<<grid(4096 * 2048), 256, 0, stream>>>(s1, s1f, nullptr, nullptr, nullptr, 4096 * 2048);
  k_prep<<<grid(4096 * 2048), 256, 0, stream>>>(s2, s2f, nullptr, sigs2b, nullptr, 4096 * 2048);
  k_prep<<<grid(40960), 256, 0, stream>>>(s3, s3f, sigs3f, nullptr, nullptr, 40960);
  k_transpose_bf16<<<dim3(1024 / 32, 2048 / 32), 256, 0, stream>>>(w0, w0tb, 1024, 2048);
  k_transpose_bf16<<<dim3(2048 / 32, 2048 / 32), 256, 0, stream>>>(w1, w1tb, 2048, 2048);

  // addcb = bf16(sig(x) @ w0 + b0)   (M=4096, N=2048, K=1024) — loop-invariant
  k_gemm<0><<<512, 256, 0, stream>>>(sigxb, w0tb, 4096, 2048, 1024,
                                     nullptr, b0, nullptr, nullptr, nullptr, addcb);

  for (int t = 0; t < 20; ++t) {
    // s1 update: pre = (sigxw0 + b0) + sig(s2)@w1^T
    k_gemm<1><<<512, 256, 0, stream>>>(sigs2b, w1b, 4096, 2048, 2048,
                                       addcb, nullptr, nullptr, nullptr, s1f, sigs1b);
    // s2 update: pre = sig(s1_new)@w1 + sig(s3)@w2^T + b1
    k_gemm<2><<<512, 256, 0, stream>>>(sigs1b, w1tb, 4096, 2048, 2048,
                                       nullptr, b1, sigs3f, w2, s2f, sigs2b);
    // s3 update: pre = sig(s2_new)@w2 + b2
    k_out<<<256, 256, 0, stream>>>(sigs2b, w2, b2, s3f, sigs3f, (t == 19) ? out : nullptr);
  }
}

// Round 4
// 2521.471 us; speedup vs baseline: 3.9456x; 1.0622x over previous
//
#include <hip/hip_runtime.h>
#include <cstdint>
#include <cstddef>

using u16 = unsigned short;
using u32 = unsigned int;

typedef __bf16 bf16x8 __attribute__((ext_vector_type(8)));
typedef float f32x4 __attribute__((ext_vector_type(4)));
typedef u16 u16x4 __attribute__((ext_vector_type(4)));

#define DEV __device__ __forceinline__

constexpr float SS = 0.1f / 20.0f;  // STEP_SIZE = DT / N_STEPS

DEV float sigm(float x) { return 1.0f / (1.0f + __expf(-x)); }

DEV u16 f2bf(float f) {  // round-to-nearest-even f32 -> bf16
  union { float f; u32 u; } v; v.f = f;
  u32 r = v.u + 0x7FFFu + ((v.u >> 16) & 1u);
  return (u16)(r >> 16);
}
DEV float bf2f(u16 h) {
  union { u32 u; float f; } v; v.u = ((u32)h) << 16;
  return v.f;
}

// ---------------------------------------------------------------------------
// prep: optional copy / sigmoid(f32) / sigmoid(bf16) / raw bf16 convert
// ---------------------------------------------------------------------------
__global__ void k_prep(const float* __restrict__ in, float* __restrict__ fcopy,
                       float* __restrict__ sigf32, u16* __restrict__ sigb,
                       u16* __restrict__ rawb, int n) {
  int stride = gridDim.x * blockDim.x;
  for (int i = blockIdx.x * blockDim.x + threadIdx.x; i < n; i += stride) {
    float v = in[i];
    if (fcopy) fcopy[i] = v;
    if (rawb) rawb[i] = f2bf(v);
    if (sigf32 || sigb) {
      float s = sigm(v);
      if (sigf32) sigf32[i] = s;
      if (sigb) sigb[i] = f2bf(s);
    }
  }
}

// out[n][k] = bf16(in[k][n]);  in: K x N f32, K,N multiples of 32
__global__ void k_transpose_bf16(const float* __restrict__ in, u16* __restrict__ out,
                                 int K, int N) {
  __shared__ float tile[32][33];
  int kb = blockIdx.x * 32, nb = blockIdx.y * 32;
  int tx = threadIdx.x & 31, ty = threadIdx.x >> 5;  // 256 threads: 32x8
#pragma unroll
  for (int i = 0; i < 4; ++i)
    tile[ty + 8 * i][tx] = in[(size_t)(kb + ty + 8 * i) * N + nb + tx];
  __syncthreads();
#pragma unroll
  for (int i = 0; i < 4; ++i)
    out[(size_t)(nb + ty + 8 * i) * K + kb + tx] = f2bf(tile[tx][ty + 8 * i]);
}

// ---------------------------------------------------------------------------
// GEMM: C = A(MxK, bf16 row-major) * Bt^T  (Bt = N x K bf16 row-major).
// 128x128 tile, BK=64, 4 waves each 64x64, 16x16x32 MFMA with SWAPPED
// operands (mfma(b,a)): lane = C-row, 4 acc regs = 4 consecutive C-cols ->
// float4/u16x4 epilogue. LDS XOR-swizzled both-sides (rule #21).
// Counted-vmcnt depth-2 pipeline (T4): prologue stages tiles 0,1; each iter:
//   compute(buf) ; barrier ; stage(buf, t+2) ; vmcnt(8) ; barrier
// vmcnt(8) = per-thread gload_lds count per K-step, so tile t+2's loads stay
// in flight across the barrier (never drain to 0 in the main loop).
// T5 setprio(1) around the MFMA cluster.
// XCD-aware 2D chunking: grid fixed 32x16 tiles = 512 blocks; xcd=b%8 owns
// an 8x8 tile region.
// MODE 0: sigb[m][n] = bf16(acc + bias[n])             (loop-invariant term)
// MODE 1: pre = acc + bf2f(addcb[m][n]); state update -> statef, sigb
// MODE 2: pre = acc + bias[n] + sum_k sig3[m][k]*w2[n*10+k]; update state
// ---------------------------------------------------------------------------
template <int MODE>
__launch_bounds__(256)
__global__ void k_gemm(const u16* __restrict__ A, const u16* __restrict__ Bt,
                       int M, int N, int K,
                       const u16* __restrict__ addcb, const float* __restrict__ bias,
                       const float* __restrict__ sig3, const float* __restrict__ w2,
                       float* __restrict__ statef, u16* __restrict__ sigb) {
  constexpr int BM = 128, BN = 128, BK = 64;
  __shared__ __align__(16) u16 Als[2][BM * BK];
  __shared__ __align__(16) u16 Bls[2][BN * BK];
  int b = blockIdx.x;
  int xcd = b & 7, slot = b >> 3;
  int tm = ((((xcd >> 1) << 3) | (slot >> 3))) * BM;  // 0..31
  int tn = ((((xcd & 1) << 3) | (slot & 7))) * BN;    // 0..15
  int tid = threadIdx.x;
  int lane = tid & 63, wid = tid >> 6;
  int l15 = lane & 15, lhi = lane >> 4;
  int wm = (wid >> 1) * 64, wn = (wid & 1) * 64;

  const u16* Ag = A + (size_t)tm * K;
  const u16* Bg = Bt + (size_t)tn * K;

  f32x4 acc[4][4] = {};

  // exactly 8 gload_lds per thread per call (the vmcnt(8) unit)
  auto stage = [&](int buf, int k0) {
#pragma unroll
    for (int rd = 0; rd < 4; ++rd) {
      int S = rd * 256 + tid;              // 16B slot index, linear in LDS
      int row = S >> 3;                    // 8 slots (128B) per 64-elem row
      int cs = ((S & 7) ^ (row & 7)) * 8;  // pre-swizzled global column
      __builtin_amdgcn_global_load_lds(
          (const __attribute__((address_space(1))) u32*)(Ag + (size_t)row * K + k0 + cs),
          (__attribute__((address_space(3))) u32*)(&Als[buf][0] + S * 8), 16, 0, 0);
      __builtin_amdgcn_global_load_lds(
          (const __attribute__((address_space(1))) u32*)(Bg + (size_t)row * K + k0 + cs),
          (__attribute__((address_space(3))) u32*)(&Bls[buf][0] + S * 8), 16, 0, 0);
    }
  };

  auto compute = [&](int buf) {
    __builtin_amdgcn_s_setprio(1);
#pragma unroll
    for (int s = 0; s < 2; ++s) {
      bf16x8 af[4], bfr[4];
#pragma unroll
      for (int i = 0; i < 4; ++i) {
        int row = wm + i * 16 + l15;
        af[i] = *(const bf16x8*)(&Als[buf][0] + row * BK + (((s * 4 + lhi) ^ (row & 7)) * 8));
      }
#pragma unroll
      for (int j = 0; j < 4; ++j) {
        int row = wn + j * 16 + l15;
        bfr[j] = *(const bf16x8*)(&Bls[buf][0] + row * BK + (((s * 4 + lhi) ^ (row & 7)) * 8));
      }
#pragma unroll
      for (int i = 0; i < 4; ++i)
#pragma unroll
        for (int j = 0; j < 4; ++j)  // SWAPPED operands
          acc[i][j] = __builtin_amdgcn_mfma_f32_16x16x32_bf16(bfr[j], af[i], acc[i][j], 0, 0, 0);
    }
    __builtin_amdgcn_s_setprio(0);
  };

  // --- counted-vmcnt depth-2 pipeline; nt even (K/64 = 16 or 32) ---
  const int nt = K / BK;
  stage(0, 0);           // 8 outstanding (tile 0)
  stage(1, BK);          // 16 outstanding (tiles 0,1)
  asm volatile("s_waitcnt vmcnt(8)" ::: "memory");  // tile 0 landed
  __builtin_amdgcn_s_barrier();
  asm volatile("" ::: "memory");

  int t = 0;
  for (; t + 3 < nt; t += 2) {
    compute(0);                                      // reads tile t (buf0)
    asm volatile("" ::: "memory");
    __builtin_amdgcn_s_barrier();                    // all waves done reading buf0
    asm volatile("" ::: "memory");
    stage(0, (t + 2) * BK);                          // restage buf0 <- tile t+2
    asm volatile("s_waitcnt vmcnt(8)" ::: "memory"); // tile t+1 landed (t+2 in flight)
    __builtin_amdgcn_s_barrier();
    asm volatile("" ::: "memory");

    compute(1);                                      // reads tile t+1 (buf1)
    asm volatile("" ::: "memory");
    __builtin_amdgcn_s_barrier();
    asm volatile("" ::: "memory");
    stage(1, (t + 3) * BK);                          // restage buf1 <- tile t+3
    asm volatile("s_waitcnt vmcnt(8)" ::: "memory"); // tile t+2 landed
    __builtin_amdgcn_s_barrier();
    asm volatile("" ::: "memory");
  }
  // t == nt-2: buf0 holds tile nt-2 (ready), buf1's tile nt-1 loads outstanding
  compute(0);
  asm volatile("s_waitcnt vmcnt(0)" ::: "memory");   // drain tile nt-1
  __builtin_amdgcn_s_barrier();
  asm volatile("" ::: "memory");
  compute(1);

  // Swapped D layout: acc[i][j][rr] = C[tm+wm+i*16+l15][tn+wn+j*16+4*lhi+rr]
  if constexpr (MODE == 0) {
#pragma unroll
    for (int i = 0; i < 4; ++i) {
      int gr = tm + wm + i * 16 + l15;
#pragma unroll
      for (int j = 0; j < 4; ++j) {
        int gc0 = tn + wn + j * 16 + 4 * lhi;
        u16x4 sb;
#pragma unroll
        for (int rr = 0; rr < 4; ++rr) sb[rr] = f2bf(acc[i][j][rr] + bias[gc0 + rr]);
        *(u16x4*)(sigb + (size_t)gr * N + gc0) = sb;
      }
    }
  } else if constexpr (MODE == 1) {
#pragma unroll
    for (int i = 0; i < 4; ++i) {
      int gr = tm + wm + i * 16 + l15;
#pragma unroll
      for (int j = 0; j < 4; ++j) {
        int gc0 = tn + wn + j * 16 + 4 * lhi;
        size_t idx = (size_t)gr * N + gc0;
        u16x4 ab = *(const u16x4*)(addcb + idx);
        f32x4 old = *(const f32x4*)(statef + idx);
        f32x4 nv; u16x4 sb;
#pragma unroll
        for (int rr = 0; rr < 4; ++rr) {
          float pre = acc[i][j][rr] + bf2f(ab[rr]);
          float o = old[rr];
          float sg = sigm(o);
          float n = o - SS * (sg * (1.0f - sg) * pre - o);
          nv[rr] = n; sb[rr] = f2bf(sigm(n));
        }
        *(f32x4*)(statef + idx) = nv;
        *(u16x4*)(sigb + idx) = sb;
      }
    }
  } else {
    float s3v[4][10];
#pragma unroll
    for (int i = 0; i < 4; ++i) {
      int gr = tm + wm + i * 16 + l15;
#pragma unroll
      for (int k = 0; k < 10; ++k) s3v[i][k] = sig3[gr * 10 + k];
    }
#pragma unroll
    for (int j = 0; j < 4; ++j) {
      int gc0 = tn + wn + j * 16 + 4 * lhi;
      float wv[4][10]; f32x4 bb;
#pragma unroll
      for (int rr = 0; rr < 4; ++rr) {
        bb[rr] = bias[gc0 + rr];
#pragma unroll
        for (int k = 0; k < 10; ++k) wv[rr][k] = w2[(gc0 + rr) * 10 + k];
      }
#pragma unroll
      for (int i = 0; i < 4; ++i) {
        int gr = tm + wm + i * 16 + l15;
        size_t idx = (size_t)gr * N + gc0;
        f32x4 old = *(const f32x4*)(statef + idx);
        f32x4 nv; u16x4 sb;
#pragma unroll
        for (int rr = 0; rr < 4; ++rr) {
          float ex = bb[rr];
#pragma unroll
          for (int k = 0; k < 10; ++k) ex += s3v[i][k] * wv[rr][k];
          float pre = acc[i][j][rr] + ex;
          float o = old[rr];
          float sg = sigm(o);
          float n = o - SS * (sg * (1.0f - sg) * pre - o);
          nv[rr] = n; sb[rr] = f2bf(sigm(n));
        }
        *(f32x4*)(statef + idx) = nv;
        *(u16x4*)(sigb + idx) = sb;
      }
    }
  }
}

// ---------------------------------------------------------------------------
// output-layer update: pre[m][n] = sum_k sig(s2_new[m][k]) * w2[k*10+n] + b2[n]
// 16 rows per block, 16 lanes per row, bf16x8 vector loads, shuffle-reduce.
// ---------------------------------------------------------------------------
__global__ void k_out(const u16* __restrict__ sigs2b, const float* __restrict__ w2,
                      const float* __restrict__ b2, float* __restrict__ s3f,
                      float* __restrict__ sigs3f, float* __restrict__ outOrNull) {
  int tid = threadIdx.x;
  int r = tid >> 4, l16 = tid & 15;
  int row = blockIdx.x * 16 + r;
  float acc[10] = {};
  const u16* arow = sigs2b + (size_t)row * 2048;
  for (int kb = l16; kb < 256; kb += 16) {  // 8 u16 per chunk, 16B coalesced
    u16x4 v0 = *(const u16x4*)(arow + kb * 8);
    u16x4 v1 = *(const u16x4*)(arow + kb * 8 + 4);
    float a[8];
#pragma unroll
    for (int e = 0; e < 4; ++e) { a[e] = bf2f(v0[e]); a[e + 4] = bf2f(v1[e]); }
    const float* wr = w2 + (size_t)kb * 80;
#pragma unroll
    for (int e = 0; e < 8; ++e)
#pragma unroll
      for (int n = 0; n < 10; ++n) acc[n] += a[e] * wr[e * 10 + n];
  }
#pragma unroll
  for (int m = 1; m < 16; m <<= 1)
#pragma unroll
    for (int n = 0; n < 10; ++n) acc[n] += __shfl_xor(acc[n], m, 64);
  if (l16 < 10) {
    float pre = 0.0f;
#pragma unroll
    for (int n = 0; n < 10; ++n)
      if (l16 == n) pre = acc[n];
    pre += b2[l16];
    size_t idx = (size_t)row * 10 + l16;
    float old = s3f[idx];
    float sg = sigm(old);
    float nv = old - SS * (sg * (1.0f - sg) * pre - old);
    s3f[idx] = nv;
    sigs3f[idx] = sigm(nv);
    if (outOrNull) outOrNull[idx] = nv;
  }
}

// ---------------------------------------------------------------------------
extern "C" void kernel_launch(void* const* d_in, const int* in_sizes, int n_in,
                              void* d_out, int out_size, void* d_ws, size_t ws_size,
                              hipStream_t stream) {
  const float* x  = (const float*)d_in[0];
  const float* w0 = (const float*)d_in[1];  // 1024 x 2048
  const float* w1 = (const float*)d_in[2];  // 2048 x 2048
  const float* w2 = (const float*)d_in[3];  // 2048 x 10
  const float* b0 = (const float*)d_in[4];
  const float* b1 = (const float*)d_in[5];
  const float* b2 = (const float*)d_in[6];
  const float* s1 = (const float*)d_in[7];
  const float* s2 = (const float*)d_in[8];
  const float* s3 = (const float*)d_in[9];
  float* out = (float*)d_out;

  uint8_t* p = (uint8_t*)d_ws;
  auto alloc = [&](size_t bytes) {
    uint8_t* r = p;
    p += (bytes + 255) & ~(size_t)255;
    return r;
  };
  float* s1f    = (float*)alloc(4096ull * 2048 * 4);
  float* s2f    = (float*)alloc(4096ull * 2048 * 4);
  u16*   addcb  = (u16*)alloc(4096ull * 2048 * 2);    // bf16(sig(x)@w0 + b0)
  u16*   sigs1b = (u16*)alloc(4096ull * 2048 * 2);
  u16*   sigs2b = (u16*)alloc(4096ull * 2048 * 2);
  u16*   sigxb  = (u16*)alloc(4096ull * 1024 * 2);
  u16*   w1b    = (u16*)alloc(2048ull * 2048 * 2);    // Bt-layout for B = w1^T
  u16*   w1tb   = (u16*)alloc(2048ull * 2048 * 2);    // Bt-layout for B = w1
  u16*   w0tb   = (u16*)alloc(2048ull * 1024 * 2);    // Bt-layout for B = w0
  float* s3f    = (float*)alloc(4096ull * 10 * 4);
  float* sigs3f = (float*)alloc(4096ull * 10 * 4);
  (void)ws_size; (void)in_sizes; (void)n_in; (void)out_size;

  auto grid = [](int n) { int g = (n + 255) / 256; return g > 2048 ? 2048 : g; };

  // one-time prep (re-done every call: poison-safe, deterministic)
  k_prep<<<grid(4096 * 1024), 256, 0, stream>>>(x, nullptr, nullptr, sigxb, nullptr, 4096 * 1024);
  k_prep<<<grid(2048 * 2048), 256, 0, stream>>>(w1, nullptr, nullptr, nullptr, w1b, 2048 * 2048);
  k_prep<<<grid(4096 * 2048), 256, 0, stream>>>(s1, s1f, nullptr, nullptr, nullptr, 4096 * 2048);
  k_prep<<<grid(4096 * 2048), 256, 0, stream>>>(s2, s2f, nullptr, sigs2b, nullptr, 4096 * 2048);
  k_prep<<<grid(40960), 256, 0, stream>>>(s3, s3f, sigs3f, nullptr, nullptr, 40960);
  k_transpose_bf16<<<dim3(1024 / 32, 2048 / 32), 256, 0, stream>>>(w0, w0tb, 1024, 2048);
  k_transpose_bf16<<<dim3(2048 / 32, 2048 / 32), 256, 0, stream>>>(w1, w1tb, 2048, 2048);

  // addcb = bf16(sig(x) @ w0 + b0)   (M=4096, N=2048, K=1024) — loop-invariant
  k_gemm<0><<<512, 256, 0, stream>>>(sigxb, w0tb, 4096, 2048, 1024,
                                     nullptr, b0, nullptr, nullptr, nullptr, addcb);

  for (int t = 0; t < 20; ++t) {
    // s1 update: pre = (sigxw0 + b0) + sig(s2)@w1^T
    k_gemm<1><<<512, 256, 0, stream>>>(sigs2b, w1b, 4096, 2048, 2048,
                                       addcb, nullptr, nullptr, nullptr, s1f, sigs1b);
    // s2 update: pre = sig(s1_new)@w1 + sig(s3)@w2^T + b1
    k_gemm<2><<<512, 256, 0, stream>>>(sigs1b, w1tb, 4096, 2048, 2048,
                                       nullptr, b1, sigs3f, w2, s2f, sigs2b);
    // s3 update: pre = sig(s2_new)@w2 + b2
    k_out<<<256, 256, 0, stream>>>(sigs2b, w2, b2, s3f, sigs3f, (t == 19) ? out : nullptr);
  }
}

// Round 5
// 2497.382 us; speedup vs baseline: 3.9837x; 1.0096x over previous
//
#include <hip/hip_runtime.h>
#include <cstdint>
#include <cstddef>

using u16 = unsigned short;
using u32 = unsigned int;

typedef __bf16 bf16x8 __attribute__((ext_vector_type(8)));
typedef float f32x4 __attribute__((ext_vector_type(4)));
typedef u16 u16x4 __attribute__((ext_vector_type(4)));

#define DEV __device__ __forceinline__

constexpr float SS = 0.1f / 20.0f;  // STEP_SIZE = DT / N_STEPS

DEV float sigm(float x) { return 1.0f / (1.0f + __expf(-x)); }

DEV u16 f2bf(float f) {  // round-to-nearest-even f32 -> bf16
  union { float f; u32 u; } v; v.f = f;
  u32 r = v.u + 0x7FFFu + ((v.u >> 16) & 1u);
  return (u16)(r >> 16);
}
DEV float bf2f(u16 h) {
  union { u32 u; float f; } v; v.u = ((u32)h) << 16;
  return v.f;
}

// ---------------------------------------------------------------------------
// prep: optional sigmoid(f32) / sigmoid(bf16) / raw bf16 convert / f32 copy
// ---------------------------------------------------------------------------
__global__ void k_prep(const float* __restrict__ in, float* __restrict__ fcopy,
                       float* __restrict__ sigf32, u16* __restrict__ sigb,
                       u16* __restrict__ rawb, int n) {
  int stride = gridDim.x * blockDim.x;
  for (int i = blockIdx.x * blockDim.x + threadIdx.x; i < n; i += stride) {
    float v = in[i];
    if (fcopy) fcopy[i] = v;
    if (rawb) rawb[i] = f2bf(v);
    if (sigf32 || sigb) {
      float s = sigm(v);
      if (sigf32) sigf32[i] = s;
      if (sigb) sigb[i] = f2bf(s);
    }
  }
}

// out[n][k] = bf16(in[k][n]);  in: K x N f32, K,N multiples of 32
__global__ void k_transpose_bf16(const float* __restrict__ in, u16* __restrict__ out,
                                 int K, int N) {
  __shared__ float tile[32][33];
  int kb = blockIdx.x * 32, nb = blockIdx.y * 32;
  int tx = threadIdx.x & 31, ty = threadIdx.x >> 5;  // 256 threads: 32x8
#pragma unroll
  for (int i = 0; i < 4; ++i)
    tile[ty + 8 * i][tx] = in[(size_t)(kb + ty + 8 * i) * N + nb + tx];
  __syncthreads();
#pragma unroll
  for (int i = 0; i < 4; ++i)
    out[(size_t)(nb + ty + 8 * i) * K + kb + tx] = f2bf(tile[tx][ty + 8 * i]);
}

// ---------------------------------------------------------------------------
// Shared tile/lane mapping for the 128x128 8-wave GEMM (512 threads).
// Wave grid 2(M) x 4(N); per-wave 64x32 output; acc[4][2] f32x4.
// C element: row gr = tm + (wid>>2)*64 + i*16 + (lane&15)
//            col gc = tn + (wid&3)*32 + j*16 + 4*(lane>>4) + rr
// Swizzle-resident buffers (statef, addcb) are stored [blk][k=i*2+j][tid][x4]
// so epilogue accesses are dense per-wave-contiguous transactions.
// ---------------------------------------------------------------------------
DEV void tile_base(int b, int& tm, int& tn) {
  int xcd = b & 7, slot = b >> 3;           // XCD-aware 2D chunking, grid 32x16
  tm = ((((xcd >> 1) << 3) | (slot >> 3))) * 128;  // 0..31
  tn = ((((xcd & 1) << 3) | (slot & 7))) * 128;    // 0..15
}

// init swizzle-resident state from a row-major M x 2048 f32 source
__global__ void k_init_state(const float* __restrict__ src, float* __restrict__ dst_swz) {
  int b = blockIdx.x;
  int tm, tn; tile_base(b, tm, tn);
  int tid = threadIdx.x, lane = tid & 63, wid = tid >> 6;
  int l15 = lane & 15, lhi = lane >> 4;
  int wm = (wid >> 2) * 64, wn = (wid & 3) * 32;
#pragma unroll
  for (int i = 0; i < 4; ++i)
#pragma unroll
    for (int j = 0; j < 2; ++j) {
      int gr = tm + wm + i * 16 + l15;
      int gc0 = tn + wn + j * 16 + 4 * lhi;
      f32x4 v = *(const f32x4*)(src + (size_t)gr * 2048 + gc0);
      *(f32x4*)(dst_swz + (((size_t)b * 8 + i * 2 + j) * 512 + tid) * 4) = v;
    }
}

// ---------------------------------------------------------------------------
// GEMM: C = A(MxK, bf16 row-major) * Bt^T  (Bt = N x K bf16 row-major).
// 128x128 tile, BK=64, 8 waves, 16x16x32 MFMA with SWAPPED operands
// (mfma(b,a)): lane = C-row, 4 acc regs = 4 consecutive C-cols.
// LDS XOR-swizzled both-sides (rule #21). Counted-vmcnt depth-2 pipeline:
//   compute(buf); barrier; stage(buf, t+2); vmcnt(4); barrier
// (4 = per-thread gload_lds per K-step; tile t+2 stays in flight).
// T5 setprio around MFMA cluster.
// MODE 0: addcb_swz[...] = bf16(acc + bias[gc])        (loop-invariant term)
// MODE 1: pre = acc + bf2f(addcb_swz); state update -> statef_swz, sigb(rm)
// MODE 2: pre = acc + bias + sum_k sig3[gr][k]*w2[gc*10+k]; update state
// ---------------------------------------------------------------------------
template <int MODE>
__launch_bounds__(512, 4)
__global__ void k_gemm(const u16* __restrict__ A, const u16* __restrict__ Bt,
                       int M, int N, int K,
                       const u16* __restrict__ addcb, const float* __restrict__ bias,
                       const float* __restrict__ sig3, const float* __restrict__ w2,
                       float* __restrict__ statef, u16* __restrict__ sigb) {
  constexpr int BM = 128, BN = 128, BK = 64;
  __shared__ __align__(16) u16 Als[2][BM * BK];
  __shared__ __align__(16) u16 Bls[2][BN * BK];
  int b = blockIdx.x;
  int tm, tn; tile_base(b, tm, tn);
  int tid = threadIdx.x;
  int lane = tid & 63, wid = tid >> 6;
  int l15 = lane & 15, lhi = lane >> 4;
  int wm = (wid >> 2) * 64, wn = (wid & 3) * 32;

  const u16* Ag = A + (size_t)tm * K;
  const u16* Bg = Bt + (size_t)tn * K;

  f32x4 acc[4][2] = {};

  // exactly 4 gload_lds per thread per call (the vmcnt(4) unit)
  auto stage = [&](int buf, int k0) {
#pragma unroll
    for (int rd = 0; rd < 2; ++rd) {
      int S = rd * 512 + tid;              // 16B slot index, linear in LDS
      int row = S >> 3;                    // 8 slots (128B) per 64-elem row
      int cs = ((S & 7) ^ (row & 7)) * 8;  // pre-swizzled global column
      __builtin_amdgcn_global_load_lds(
          (const __attribute__((address_space(1))) u32*)(Ag + (size_t)row * K + k0 + cs),
          (__attribute__((address_space(3))) u32*)(&Als[buf][0] + S * 8), 16, 0, 0);
      __builtin_amdgcn_global_load_lds(
          (const __attribute__((address_space(1))) u32*)(Bg + (size_t)row * K + k0 + cs),
          (__attribute__((address_space(3))) u32*)(&Bls[buf][0] + S * 8), 16, 0, 0);
    }
  };

  auto compute = [&](int buf) {
    __builtin_amdgcn_s_setprio(1);
#pragma unroll
    for (int s = 0; s < 2; ++s) {
      bf16x8 af[4], bfr[2];
#pragma unroll
      for (int i = 0; i < 4; ++i) {
        int row = wm + i * 16 + l15;
        af[i] = *(const bf16x8*)(&Als[buf][0] + row * BK + (((s * 4 + lhi) ^ (row & 7)) * 8));
      }
#pragma unroll
      for (int j = 0; j < 2; ++j) {
        int row = wn + j * 16 + l15;
        bfr[j] = *(const bf16x8*)(&Bls[buf][0] + row * BK + (((s * 4 + lhi) ^ (row & 7)) * 8));
      }
#pragma unroll
      for (int i = 0; i < 4; ++i)
#pragma unroll
        for (int j = 0; j < 2; ++j)  // SWAPPED operands
          acc[i][j] = __builtin_amdgcn_mfma_f32_16x16x32_bf16(bfr[j], af[i], acc[i][j], 0, 0, 0);
    }
    __builtin_amdgcn_s_setprio(0);
  };

  // --- counted-vmcnt depth-2 pipeline; nt even (K/64 = 16 or 32) ---
  const int nt = K / BK;
  stage(0, 0);           // 4 outstanding (tile 0)
  stage(1, BK);          // 8 outstanding (tiles 0,1)
  asm volatile("s_waitcnt vmcnt(4)" ::: "memory");  // tile 0 landed
  __builtin_amdgcn_s_barrier();
  asm volatile("" ::: "memory");

  int t = 0;
  for (; t + 3 < nt; t += 2) {
    compute(0);                                      // reads tile t (buf0)
    asm volatile("" ::: "memory");
    __builtin_amdgcn_s_barrier();                    // all waves done reading buf0
    asm volatile("" ::: "memory");
    stage(0, (t + 2) * BK);                          // restage buf0 <- tile t+2
    asm volatile("s_waitcnt vmcnt(4)" ::: "memory"); // tile t+1 landed (t+2 in flight)
    __builtin_amdgcn_s_barrier();
    asm volatile("" ::: "memory");

    compute(1);                                      // reads tile t+1 (buf1)
    asm volatile("" ::: "memory");
    __builtin_amdgcn_s_barrier();
    asm volatile("" ::: "memory");
    stage(1, (t + 3) * BK);                          // restage buf1 <- tile t+3
    asm volatile("s_waitcnt vmcnt(4)" ::: "memory"); // tile t+2 landed
    __builtin_amdgcn_s_barrier();
    asm volatile("" ::: "memory");
  }
  // t == nt-2: buf0 holds tile nt-2 (ready), buf1's tile nt-1 loads outstanding
  compute(0);
  asm volatile("s_waitcnt vmcnt(0)" ::: "memory");   // drain tile nt-1
  __builtin_amdgcn_s_barrier();
  asm volatile("" ::: "memory");
  compute(1);

  // Epilogue. Swapped D layout:
  //   acc[i][j][rr] = C[tm+wm+i*16+l15][tn+wn+j*16+4*lhi+rr]
  // statef/addcb are swizzle-resident: index (((b*8 + i*2+j)*512 + tid)*4 + rr)
  if constexpr (MODE == 0) {
#pragma unroll
    for (int i = 0; i < 4; ++i)
#pragma unroll
      for (int j = 0; j < 2; ++j) {
        int gc0 = tn + wn + j * 16 + 4 * lhi;
        size_t sidx = (((size_t)b * 8 + i * 2 + j) * 512 + tid) * 4;
        u16x4 sb;
#pragma unroll
        for (int rr = 0; rr < 4; ++rr) sb[rr] = f2bf(acc[i][j][rr] + bias[gc0 + rr]);
        *(u16x4*)(sigb + sidx) = sb;  // sigb arg doubles as addcb_swz output
      }
  } else if constexpr (MODE == 1) {
#pragma unroll
    for (int i = 0; i < 4; ++i)
#pragma unroll
      for (int j = 0; j < 2; ++j) {
        int gr = tm + wm + i * 16 + l15;
        int gc0 = tn + wn + j * 16 + 4 * lhi;
        size_t sidx = (((size_t)b * 8 + i * 2 + j) * 512 + tid) * 4;
        u16x4 ab = *(const u16x4*)(addcb + sidx);
        f32x4 old = *(const f32x4*)(statef + sidx);
        f32x4 nv; u16x4 sb;
#pragma unroll
        for (int rr = 0; rr < 4; ++rr) {
          float pre = acc[i][j][rr] + bf2f(ab[rr]);
          float o = old[rr];
          float sg = sigm(o);
          float n = o - SS * (sg * (1.0f - sg) * pre - o);
          nv[rr] = n; sb[rr] = f2bf(sigm(n));
        }
        *(f32x4*)(statef + sidx) = nv;
        *(u16x4*)(sigb + (size_t)gr * N + gc0) = sb;  // row-major (feeds next GEMM A)
      }
  } else {
    float s3v[4][10];
#pragma unroll
    for (int i = 0; i < 4; ++i) {
      int gr = tm + wm + i * 16 + l15;
#pragma unroll
      for (int k = 0; k < 10; ++k) s3v[i][k] = sig3[gr * 10 + k];
    }
#pragma unroll
    for (int j = 0; j < 2; ++j) {
      int gc0 = tn + wn + j * 16 + 4 * lhi;
      float wv[4][10]; f32x4 bb;
#pragma unroll
      for (int rr = 0; rr < 4; ++rr) {
        bb[rr] = bias[gc0 + rr];
#pragma unroll
        for (int k = 0; k < 10; ++k) wv[rr][k] = w2[(gc0 + rr) * 10 + k];
      }
#pragma unroll
      for (int i = 0; i < 4; ++i) {
        int gr = tm + wm + i * 16 + l15;
        size_t sidx = (((size_t)b * 8 + i * 2 + j) * 512 + tid) * 4;
        f32x4 old = *(const f32x4*)(statef + sidx);
        f32x4 nv; u16x4 sb;
#pragma unroll
        for (int rr = 0; rr < 4; ++rr) {
          float ex = bb[rr];
#pragma unroll
          for (int k = 0; k < 10; ++k) ex += s3v[i][k] * wv[rr][k];
          float pre = acc[i][j][rr] + ex;
          float o = old[rr];
          float sg = sigm(o);
          float n = o - SS * (sg * (1.0f - sg) * pre - o);
          nv[rr] = n; sb[rr] = f2bf(sigm(n));
        }
        *(f32x4*)(statef + sidx) = nv;
        *(u16x4*)(sigb + (size_t)gr * N + gc0) = sb;
      }
    }
  }
}

// ---------------------------------------------------------------------------
// output-layer update: pre[m][n] = sum_k sig(s2_new[m][k]) * w2[k*10+n] + b2[n]
// 16 rows per block, 16 lanes per row, bf16x8 vector loads, shuffle-reduce.
// ---------------------------------------------------------------------------
__global__ void k_out(const u16* __restrict__ sigs2b, const float* __restrict__ w2,
                      const float* __restrict__ b2, float* __restrict__ s3f,
                      float* __restrict__ sigs3f, float* __restrict__ outOrNull) {
  int tid = threadIdx.x;
  int r = tid >> 4, l16 = tid & 15;
  int row = blockIdx.x * 16 + r;
  float acc[10] = {};
  const u16* arow = sigs2b + (size_t)row * 2048;
  for (int kb = l16; kb < 256; kb += 16) {  // 8 u16 per chunk, 16B coalesced
    u16x4 v0 = *(const u16x4*)(arow + kb * 8);
    u16x4 v1 = *(const u16x4*)(arow + kb * 8 + 4);
    float a[8];
#pragma unroll
    for (int e = 0; e < 4; ++e) { a[e] = bf2f(v0[e]); a[e + 4] = bf2f(v1[e]); }
    const float* wr = w2 + (size_t)kb * 80;
#pragma unroll
    for (int e = 0; e < 8; ++e)
#pragma unroll
      for (int n = 0; n < 10; ++n) acc[n] += a[e] * wr[e * 10 + n];
  }
#pragma unroll
  for (int m = 1; m < 16; m <<= 1)
#pragma unroll
    for (int n = 0; n < 10; ++n) acc[n] += __shfl_xor(acc[n], m, 64);
  if (l16 < 10) {
    float pre = 0.0f;
#pragma unroll
    for (int n = 0; n < 10; ++n)
      if (l16 == n) pre = acc[n];
    pre += b2[l16];
    size_t idx = (size_t)row * 10 + l16;
    float old = s3f[idx];
    float sg = sigm(old);
    float nv = old - SS * (sg * (1.0f - sg) * pre - old);
    s3f[idx] = nv;
    sigs3f[idx] = sigm(nv);
    if (outOrNull) outOrNull[idx] = nv;
  }
}

// ---------------------------------------------------------------------------
extern "C" void kernel_launch(void* const* d_in, const int* in_sizes, int n_in,
                              void* d_out, int out_size, void* d_ws, size_t ws_size,
                              hipStream_t stream) {
  const float* x  = (const float*)d_in[0];
  const float* w0 = (const float*)d_in[1];  // 1024 x 2048
  const float* w1 = (const float*)d_in[2];  // 2048 x 2048
  const float* w2 = (const float*)d_in[3];  // 2048 x 10
  const float* b0 = (const float*)d_in[4];
  const float* b1 = (const float*)d_in[5];
  const float* b2 = (const float*)d_in[6];
  const float* s1 = (const float*)d_in[7];
  const float* s2 = (const float*)d_in[8];
  const float* s3 = (const float*)d_in[9];
  float* out = (float*)d_out;

  uint8_t* p = (uint8_t*)d_ws;
  auto alloc = [&](size_t bytes) {
    uint8_t* r = p;
    p += (bytes + 255) & ~(size_t)255;
    return r;
  };
  float* s1f    = (float*)alloc(4096ull * 2048 * 4);  // swizzle-resident
  float* s2f    = (float*)alloc(4096ull * 2048 * 4);  // swizzle-resident
  u16*   addcb  = (u16*)alloc(4096ull * 2048 * 2);    // swizzle-resident
  u16*   sigs1b = (u16*)alloc(4096ull * 2048 * 2);    // row-major
  u16*   sigs2b = (u16*)alloc(4096ull * 2048 * 2);    // row-major
  u16*   sigxb  = (u16*)alloc(4096ull * 1024 * 2);
  u16*   w1b    = (u16*)alloc(2048ull * 2048 * 2);    // Bt-layout for B = w1^T
  u16*   w1tb   = (u16*)alloc(2048ull * 2048 * 2);    // Bt-layout for B = w1
  u16*   w0tb   = (u16*)alloc(2048ull * 1024 * 2);    // Bt-layout for B = w0
  float* s3f    = (float*)alloc(4096ull * 10 * 4);
  float* sigs3f = (float*)alloc(4096ull * 10 * 4);
  (void)ws_size; (void)in_sizes; (void)n_in; (void)out_size;

  auto grid = [](int n) { int g = (n + 255) / 256; return g > 2048 ? 2048 : g; };

  // one-time prep (re-done every call: poison-safe, deterministic)
  k_prep<<<grid(4096 * 1024), 256, 0, stream>>>(x, nullptr, nullptr, sigxb, nullptr, 4096 * 1024);
  k_prep<<<grid(2048 * 2048), 256, 0, stream>>>(w1, nullptr, nullptr, nullptr, w1b, 2048 * 2048);
  k_prep<<<grid(4096 * 2048), 256, 0, stream>>>(s2, nullptr, nullptr, sigs2b, nullptr, 4096 * 2048);
  k_prep<<<grid(40960), 256, 0, stream>>>(s3, s3f, sigs3f, nullptr, nullptr, 40960);
  k_init_state<<<512, 512, 0, stream>>>(s1, s1f);
  k_init_state<<<512, 512, 0, stream>>>(s2, s2f);
  k_transpose_bf16<<<dim3(1024 / 32, 2048 / 32), 256, 0, stream>>>(w0, w0tb, 1024, 2048);
  k_transpose_bf16<<<dim3(2048 / 32, 2048 / 32), 256, 0, stream>>>(w1, w1tb, 2048, 2048);

  // addcb = bf16(sig(x) @ w0 + b0)   (M=4096, N=2048, K=1024) — loop-invariant
  k_gemm<0><<<512, 512, 0, stream>>>(sigxb, w0tb, 4096, 2048, 1024,
                                     nullptr, b0, nullptr, nullptr, nullptr, addcb);

  for (int t = 0; t < 20; ++t) {
    // s1 update: pre = (sigxw0 + b0) + sig(s2)@w1^T
    k_gemm<1><<<512, 512, 0, stream>>>(sigs2b, w1b, 4096, 2048, 2048,
                                       addcb, nullptr, nullptr, nullptr, s1f, sigs1b);
    // s2 update: pre = sig(s1_new)@w1 + sig(s3)@w2^T + b1
    k_gemm<2><<<512, 512, 0, stream>>>(sigs1b, w1tb, 4096, 2048, 2048,
                                       nullptr, b1, sigs3f, w2, s2f, sigs2b);
    // s3 update: pre = sig(s2_new)@w2 + b2
    k_out<<<256, 256, 0, stream>>>(sigs2b, w2, b2, s3f, sigs3f, (t == 19) ? out : nullptr);
  }
}

// Round 6
// 2493.339 us; speedup vs baseline: 3.9901x; 1.0016x over previous
//
#include <hip/hip_runtime.h>
#include <cstdint>
#include <cstddef>

using u16 = unsigned short;
using u32 = unsigned int;

typedef __bf16 bf16x8 __attribute__((ext_vector_type(8)));
typedef float f32x4 __attribute__((ext_vector_type(4)));
typedef u16 u16x4 __attribute__((ext_vector_type(4)));

#define DEV __device__ __forceinline__

constexpr float SS = 0.1f / 20.0f;  // STEP_SIZE = DT / N_STEPS

DEV float sigm(float x) { return 1.0f / (1.0f + __expf(-x)); }

DEV u16 f2bf(float f) {  // round-to-nearest-even f32 -> bf16
  union { float f; u32 u; } v; v.f = f;
  u32 r = v.u + 0x7FFFu + ((v.u >> 16) & 1u);
  return (u16)(r >> 16);
}
DEV float bf2f(u16 h) {
  union { u32 u; float f; } v; v.u = ((u32)h) << 16;
  return v.f;
}

// ---------------------------------------------------------------------------
// prep: optional sigmoid(f32) / sigmoid(bf16) / raw bf16 convert / f32 copy
// ---------------------------------------------------------------------------
__global__ void k_prep(const float* __restrict__ in, float* __restrict__ fcopy,
                       float* __restrict__ sigf32, u16* __restrict__ sigb,
                       u16* __restrict__ rawb, int n) {
  int stride = gridDim.x * blockDim.x;
  for (int i = blockIdx.x * blockDim.x + threadIdx.x; i < n; i += stride) {
    float v = in[i];
    if (fcopy) fcopy[i] = v;
    if (rawb) rawb[i] = f2bf(v);
    if (sigf32 || sigb) {
      float s = sigm(v);
      if (sigf32) sigf32[i] = s;
      if (sigb) sigb[i] = f2bf(s);
    }
  }
}

// out[n][k] = bf16(in[k][n]);  in: K x N f32, K,N multiples of 32
__global__ void k_transpose_bf16(const float* __restrict__ in, u16* __restrict__ out,
                                 int K, int N) {
  __shared__ float tile[32][33];
  int kb = blockIdx.x * 32, nb = blockIdx.y * 32;
  int tx = threadIdx.x & 31, ty = threadIdx.x >> 5;  // 256 threads: 32x8
#pragma unroll
  for (int i = 0; i < 4; ++i)
    tile[ty + 8 * i][tx] = in[(size_t)(kb + ty + 8 * i) * N + nb + tx];
  __syncthreads();
#pragma unroll
  for (int i = 0; i < 4; ++i)
    out[(size_t)(nb + ty + 8 * i) * K + kb + tx] = f2bf(tile[tx][ty + 8 * i]);
}

// ---------------------------------------------------------------------------
// Geometry: 256x128 tile, grid 16(M) x 16(N) = 256 blocks (1/CU), 512 thr.
// Wave grid 4(M) x 2(N); per-wave 64x64 output; acc[4][4] f32x4.
// C element: row gr = tm + (wid>>1)*64 + i*16 + (lane&15)
//            col gc = tn + (wid&1)*64 + j*16 + 4*(lane>>4) + rr
// Swizzle-resident buffers (statef, addcb): [blk][k=i*4+j][tid][x4].
// XCD chunking: xcd=b&7 owns a 4x8 tile region (A strip 4MB, B strip 4MB).
// ---------------------------------------------------------------------------
DEV void tile_base(int b, int& tm, int& tn) {
  int xcd = b & 7, slot = b >> 3;                  // slot 0..31
  tm = ((xcd >> 1) * 4 + (slot >> 3)) * 256;       // 16 M-tiles
  tn = ((xcd & 1) * 8 + (slot & 7)) * 128;         // 16 N-tiles
}

// init swizzle-resident state from a row-major M x 2048 f32 source
__global__ void k_init_state(const float* __restrict__ src, float* __restrict__ dst_swz) {
  int b = blockIdx.x;
  int tm, tn; tile_base(b, tm, tn);
  int tid = threadIdx.x, lane = tid & 63, wid = tid >> 6;
  int l15 = lane & 15, lhi = lane >> 4;
  int wm = (wid >> 1) * 64, wn = (wid & 1) * 64;
#pragma unroll
  for (int i = 0; i < 4; ++i)
#pragma unroll
    for (int j = 0; j < 4; ++j) {
      int gr = tm + wm + i * 16 + l15;
      int gc0 = tn + wn + j * 16 + 4 * lhi;
      f32x4 v = *(const f32x4*)(src + (size_t)gr * 2048 + gc0);
      *(f32x4*)(dst_swz + (((size_t)b * 16 + i * 4 + j) * 512 + tid) * 4) = v;
    }
}

// ---------------------------------------------------------------------------
// GEMM: C = A(MxK, bf16 rm) * Bt^T (Bt = N x K bf16 rm). 256x128 tile, BK=64,
// 8 waves, 16x16x32 MFMA SWAPPED (mfma(b,a)): lane = C-row, regs = 4 C-cols.
// LDS XOR-swizzle both-sides (rule #21). TRIPLE-buffered staging (144 KB
// dynamic LDS), depth-3 counted vmcnt: per phase
//   vmcnt(12); bar; compute(p); bar; stage(p, t+3)
// so the awaited tile was issued 3 phases (~3700cy) earlier >> HBM latency.
// T5 setprio around MFMA cluster.
// MODE 0: addcb_swz = bf16(acc + bias[gc])             (loop-invariant term)
// MODE 1: pre = acc + bf2f(addcb_swz); state update -> statef_swz, sigb(rm)
// MODE 2: pre = acc + bias + sum_k sig3[gr][k]*w2[gc*10+k]; update state
// ---------------------------------------------------------------------------
template <int MODE>
__launch_bounds__(512, 2)
__global__ void k_gemm(const u16* __restrict__ A, const u16* __restrict__ Bt,
                       int M, int N, int K,
                       const u16* __restrict__ addcb, const float* __restrict__ bias,
                       const float* __restrict__ sig3, const float* __restrict__ w2,
                       float* __restrict__ statef, u16* __restrict__ sigb) {
  constexpr int BK = 64;
  extern __shared__ __align__(16) u16 lds_dyn[];   // 3*16384 (A) + 3*8192 (B)
  u16* const AlsBase = lds_dyn;
  u16* const BlsBase = lds_dyn + 3 * 16384;

  int b = blockIdx.x;
  int tm, tn; tile_base(b, tm, tn);
  int tid = threadIdx.x;
  int lane = tid & 63, wid = tid >> 6;
  int l15 = lane & 15, lhi = lane >> 4;
  int wm = (wid >> 1) * 64, wn = (wid & 1) * 64;

  const u16* Ag = A + (size_t)tm * K;
  const u16* Bg = Bt + (size_t)tn * K;

  f32x4 acc[4][4] = {};

  // 6 gload_lds per thread per call: 4 for A (256x64), 2 for B (128x64)
  auto stage = [&](int p, int k0) {
    u16* Ap = AlsBase + p * 16384;
    u16* Bp = BlsBase + p * 8192;
#pragma unroll
    for (int rd = 0; rd < 4; ++rd) {
      int S = rd * 512 + tid;              // A 16B-slot 0..2047
      int row = S >> 3;                    // 8 slots (128B) per 64-elem row
      int cs = ((S & 7) ^ (row & 7)) * 8;  // pre-swizzled global column
      __builtin_amdgcn_global_load_lds(
          (const __attribute__((address_space(1))) u32*)(Ag + (size_t)row * K + k0 + cs),
          (__attribute__((address_space(3))) u32*)(Ap + S * 8), 16, 0, 0);
    }
#pragma unroll
    for (int rd = 0; rd < 2; ++rd) {
      int S = rd * 512 + tid;              // B 16B-slot 0..1023
      int row = S >> 3;
      int cs = ((S & 7) ^ (row & 7)) * 8;
      __builtin_amdgcn_global_load_lds(
          (const __attribute__((address_space(1))) u32*)(Bg + (size_t)row * K + k0 + cs),
          (__attribute__((address_space(3))) u32*)(Bp + S * 8), 16, 0, 0);
    }
  };

  auto compute = [&](int p) {
    const u16* Ap = AlsBase + p * 16384;
    const u16* Bp = BlsBase + p * 8192;
    __builtin_amdgcn_s_setprio(1);
#pragma unroll
    for (int s = 0; s < 2; ++s) {
      bf16x8 af[4], bfr[4];
#pragma unroll
      for (int i = 0; i < 4; ++i) {
        int row = wm + i * 16 + l15;         // 0..255
        af[i] = *(const bf16x8*)(Ap + row * BK + (((s * 4 + lhi) ^ (row & 7)) * 8));
      }
#pragma unroll
      for (int j = 0; j < 4; ++j) {
        int row = wn + j * 16 + l15;         // 0..127
        bfr[j] = *(const bf16x8*)(Bp + row * BK + (((s * 4 + lhi) ^ (row & 7)) * 8));
      }
#pragma unroll
      for (int i = 0; i < 4; ++i)
#pragma unroll
        for (int j = 0; j < 4; ++j)  // SWAPPED operands
          acc[i][j] = __builtin_amdgcn_mfma_f32_16x16x32_bf16(bfr[j], af[i], acc[i][j], 0, 0, 0);
    }
    __builtin_amdgcn_s_setprio(0);
  };

  // --- depth-3 counted-vmcnt pipeline; nt = K/64 (16 or 32) ---
  const int nt = K / BK;
  stage(0, 0); stage(1, BK); stage(2, 2 * BK);     // 18 outstanding
  int p = 0;
  for (int t = 0; t < nt - 3; ++t) {
    asm volatile("s_waitcnt vmcnt(12)" ::: "memory");  // tile t landed
    __builtin_amdgcn_s_barrier();
    asm volatile("" ::: "memory");
    compute(p);
    asm volatile("" ::: "memory");
    __builtin_amdgcn_s_barrier();                      // all done reading buf p
    asm volatile("" ::: "memory");
    stage(p, (t + 3) * BK);                            // buf p <- tile t+3
    p = (p == 2) ? 0 : p + 1;
  }
  // tail: tiles nt-3, nt-2, nt-1 (no more staging)
  asm volatile("s_waitcnt vmcnt(12)" ::: "memory");
  __builtin_amdgcn_s_barrier();
  asm volatile("" ::: "memory");
  compute(p); p = (p == 2) ? 0 : p + 1;
  asm volatile("s_waitcnt vmcnt(6)" ::: "memory");
  __builtin_amdgcn_s_barrier();
  asm volatile("" ::: "memory");
  compute(p); p = (p == 2) ? 0 : p + 1;
  asm volatile("s_waitcnt vmcnt(0)" ::: "memory");
  __builtin_amdgcn_s_barrier();
  asm volatile("" ::: "memory");
  compute(p);

  // Epilogue. acc[i][j][rr] = C[tm+wm+i*16+l15][tn+wn+j*16+4*lhi+rr]
  // swizzle-resident index: (((b*16 + i*4+j)*512 + tid)*4 + rr)
  if constexpr (MODE == 0) {
#pragma unroll
    for (int i = 0; i < 4; ++i)
#pragma unroll
      for (int j = 0; j < 4; ++j) {
        int gc0 = tn + wn + j * 16 + 4 * lhi;
        size_t sidx = (((size_t)b * 16 + i * 4 + j) * 512 + tid) * 4;
        u16x4 sb;
#pragma unroll
        for (int rr = 0; rr < 4; ++rr) sb[rr] = f2bf(acc[i][j][rr] + bias[gc0 + rr]);
        *(u16x4*)(sigb + sidx) = sb;  // sigb arg doubles as addcb_swz output
      }
  } else if constexpr (MODE == 1) {
#pragma unroll
    for (int i = 0; i < 4; ++i)
#pragma unroll
      for (int j = 0; j < 4; ++j) {
        int gr = tm + wm + i * 16 + l15;
        int gc0 = tn + wn + j * 16 + 4 * lhi;
        size_t sidx = (((size_t)b * 16 + i * 4 + j) * 512 + tid) * 4;
        u16x4 ab = *(const u16x4*)(addcb + sidx);
        f32x4 old = *(const f32x4*)(statef + sidx);
        f32x4 nv; u16x4 sb;
#pragma unroll
        for (int rr = 0; rr < 4; ++rr) {
          float pre = acc[i][j][rr] + bf2f(ab[rr]);
          float o = old[rr];
          float sg = sigm(o);
          float n = o - SS * (sg * (1.0f - sg) * pre - o);
          nv[rr] = n; sb[rr] = f2bf(sigm(n));
        }
        *(f32x4*)(statef + sidx) = nv;
        *(u16x4*)(sigb + (size_t)gr * N + gc0) = sb;  // row-major (next GEMM's A)
      }
  } else {
    float s3v[4][10];
#pragma unroll
    for (int i = 0; i < 4; ++i) {
      int gr = tm + wm + i * 16 + l15;
#pragma unroll
      for (int k = 0; k < 10; ++k) s3v[i][k] = sig3[gr * 10 + k];
    }
#pragma unroll
    for (int j = 0; j < 4; ++j) {
      int gc0 = tn + wn + j * 16 + 4 * lhi;
      float wv[4][10]; f32x4 bb;
#pragma unroll
      for (int rr = 0; rr < 4; ++rr) {
        bb[rr] = bias[gc0 + rr];
#pragma unroll
        for (int k = 0; k < 10; ++k) wv[rr][k] = w2[(gc0 + rr) * 10 + k];
      }
#pragma unroll
      for (int i = 0; i < 4; ++i) {
        int gr = tm + wm + i * 16 + l15;
        size_t sidx = (((size_t)b * 16 + i * 4 + j) * 512 + tid) * 4;
        f32x4 old = *(const f32x4*)(statef + sidx);
        f32x4 nv; u16x4 sb;
#pragma unroll
        for (int rr = 0; rr < 4; ++rr) {
          float ex = bb[rr];
#pragma unroll
          for (int k = 0; k < 10; ++k) ex += s3v[i][k] * wv[rr][k];
          float pre = acc[i][j][rr] + ex;
          float o = old[rr];
          float sg = sigm(o);
          float n = o - SS * (sg * (1.0f - sg) * pre - o);
          nv[rr] = n; sb[rr] = f2bf(sigm(n));
        }
        *(f32x4*)(statef + sidx) = nv;
        *(u16x4*)(sigb + (size_t)gr * N + gc0) = sb;
      }
    }
  }
}

// ---------------------------------------------------------------------------
// output-layer update: pre[m][n] = sum_k sig(s2_new[m][k]) * w2[k*10+n] + b2[n]
// 16 rows per block, 16 lanes per row, bf16x8 vector loads, shuffle-reduce.
// ---------------------------------------------------------------------------
__global__ void k_out(const u16* __restrict__ sigs2b, const float* __restrict__ w2,
                      const float* __restrict__ b2, float* __restrict__ s3f,
                      float* __restrict__ sigs3f, float* __restrict__ outOrNull) {
  int tid = threadIdx.x;
  int r = tid >> 4, l16 = tid & 15;
  int row = blockIdx.x * 16 + r;
  float acc[10] = {};
  const u16* arow = sigs2b + (size_t)row * 2048;
  for (int kb = l16; kb < 256; kb += 16) {  // 8 u16 per chunk, 16B coalesced
    u16x4 v0 = *(const u16x4*)(arow + kb * 8);
    u16x4 v1 = *(const u16x4*)(arow + kb * 8 + 4);
    float a[8];
#pragma unroll
    for (int e = 0; e < 4; ++e) { a[e] = bf2f(v0[e]); a[e + 4] = bf2f(v1[e]); }
    const float* wr = w2 + (size_t)kb * 80;
#pragma unroll
    for (int e = 0; e < 8; ++e)
#pragma unroll
      for (int n = 0; n < 10; ++n) acc[n] += a[e] * wr[e * 10 + n];
  }
#pragma unroll
  for (int m = 1; m < 16; m <<= 1)
#pragma unroll
    for (int n = 0; n < 10; ++n) acc[n] += __shfl_xor(acc[n], m, 64);
  if (l16 < 10) {
    float pre = 0.0f;
#pragma unroll
    for (int n = 0; n < 10; ++n)
      if (l16 == n) pre = acc[n];
    pre += b2[l16];
    size_t idx = (size_t)row * 10 + l16;
    float old = s3f[idx];
    float sg = sigm(old);
    float nv = old - SS * (sg * (1.0f - sg) * pre - old);
    s3f[idx] = nv;
    sigs3f[idx] = sigm(nv);
    if (outOrNull) outOrNull[idx] = nv;
  }
}

// ---------------------------------------------------------------------------
extern "C" void kernel_launch(void* const* d_in, const int* in_sizes, int n_in,
                              void* d_out, int out_size, void* d_ws, size_t ws_size,
                              hipStream_t stream) {
  const float* x  = (const float*)d_in[0];
  const float* w0 = (const float*)d_in[1];  // 1024 x 2048
  const float* w1 = (const float*)d_in[2];  // 2048 x 2048
  const float* w2 = (const float*)d_in[3];  // 2048 x 10
  const float* b0 = (const float*)d_in[4];
  const float* b1 = (const float*)d_in[5];
  const float* b2 = (const float*)d_in[6];
  const float* s1 = (const float*)d_in[7];
  const float* s2 = (const float*)d_in[8];
  const float* s3 = (const float*)d_in[9];
  float* out = (float*)d_out;

  uint8_t* p = (uint8_t*)d_ws;
  auto alloc = [&](size_t bytes) {
    uint8_t* r = p;
    p += (bytes + 255) & ~(size_t)255;
    return r;
  };
  float* s1f    = (float*)alloc(4096ull * 2048 * 4);  // swizzle-resident
  float* s2f    = (float*)alloc(4096ull * 2048 * 4);  // swizzle-resident
  u16*   addcb  = (u16*)alloc(4096ull * 2048 * 2);    // swizzle-resident
  u16*   sigs1b = (u16*)alloc(4096ull * 2048 * 2);    // row-major
  u16*   sigs2b = (u16*)alloc(4096ull * 2048 * 2);    // row-major
  u16*   sigxb  = (u16*)alloc(4096ull * 1024 * 2);
  u16*   w1b    = (u16*)alloc(2048ull * 2048 * 2);    // Bt-layout for B = w1^T
  u16*   w1tb   = (u16*)alloc(2048ull * 2048 * 2);    // Bt-layout for B = w1
  u16*   w0tb   = (u16*)alloc(2048ull * 1024 * 2);    // Bt-layout for B = w0
  float* s3f    = (float*)alloc(4096ull * 10 * 4);
  float* sigs3f = (float*)alloc(4096ull * 10 * 4);
  (void)ws_size; (void)in_sizes; (void)n_in; (void)out_size;

  constexpr int LDS_BYTES = 3 * (16384 + 8192) * 2;  // 144 KB
  (void)hipFuncSetAttribute((const void*)k_gemm<0>,
      hipFuncAttributeMaxDynamicSharedMemorySize, LDS_BYTES);
  (void)hipFuncSetAttribute((const void*)k_gemm<1>,
      hipFuncAttributeMaxDynamicSharedMemorySize, LDS_BYTES);
  (void)hipFuncSetAttribute((const void*)k_gemm<2>,
      hipFuncAttributeMaxDynamicSharedMemorySize, LDS_BYTES);

  auto grid = [](int n) { int g = (n + 255) / 256; return g > 2048 ? 2048 : g; };

  // one-time prep (re-done every call: poison-safe, deterministic)
  k_prep<<<grid(4096 * 1024), 256, 0, stream>>>(x, nullptr, nullptr, sigxb, nullptr, 4096 * 1024);
  k_prep<<<grid(2048 * 2048), 256, 0, stream>>>(w1, nullptr, nullptr, nullptr, w1b, 2048 * 2048);
  k_prep<<<grid(4096 * 2048), 256, 0, stream>>>(s2, nullptr, nullptr, sigs2b, nullptr, 4096 * 2048);
  k_prep<<<grid(40960), 256, 0, stream>>>(s3, s3f, sigs3f, nullptr, nullptr, 40960);
  k_init_state<<<256, 512, 0, stream>>>(s1, s1f);
  k_init_state<<<256, 512, 0, stream>>>(s2, s2f);
  k_transpose_bf16<<<dim3(1024 / 32, 2048 / 32), 256, 0, stream>>>(w0, w0tb, 1024, 2048);
  k_transpose_bf16<<<dim3(2048 / 32, 2048 / 32), 256, 0, stream>>>(w1, w1tb, 2048, 2048);

  // addcb = bf16(sig(x) @ w0 + b0)   (M=4096, N=2048, K=1024) — loop-invariant
  k_gemm<0><<<256, 512, LDS_BYTES, stream>>>(sigxb, w0tb, 4096, 2048, 1024,
                                             nullptr, b0, nullptr, nullptr, nullptr, addcb);

  for (int t = 0; t < 20; ++t) {
    // s1 update: pre = (sigxw0 + b0) + sig(s2)@w1^T
    k_gemm<1><<<256, 512, LDS_BYTES, stream>>>(sigs2b, w1b, 4096, 2048, 2048,
                                               addcb, nullptr, nullptr, nullptr, s1f, sigs1b);
    // s2 update: pre = sig(s1_new)@w1 + sig(s3)@w2^T + b1
    k_gemm<2><<<256, 512, LDS_BYTES, stream>>>(sigs1b, w1tb, 4096, 2048, 2048,
                                               nullptr, b1, sigs3f, w2, s2f, sigs2b);
    // s3 update: pre = sig(s2_new)@w2 + b2
    k_out<<<256, 256, 0, stream>>>(sigs2b, w2, b2, s3f, sigs3f, (t == 19) ? out : nullptr);
  }
}